// Round 14
// baseline (656.367 us; speedup 1.0000x reference)
//
#include <hip/hip_runtime.h>

#define NN 100000
#define NE 1600000

typedef __attribute__((ext_vector_type(8))) short bf16x8;
typedef __attribute__((ext_vector_type(4))) float f32x4;

// ---------------------------------------------------------------------------
// Workspace layout in 4-byte units (~296 MB; round-5 tier-1 proved >=494 MB)
// ---------------------------------------------------------------------------
#define OFF_M    0                         // 128*128 folded [A | wu1_top]
#define OFF_B    (OFF_M + 16384)           // 32*64   we @ wm1_bot (fp32)
#define OFF_C    (OFF_B + 2048)            // 64      folded msg bias
#define OFF_W2U  (OFF_C + 64)              // 64*64   wm2 @ wu1_bot
#define OFF_D2   (OFF_W2U + 4096)          // 64      bm2 @ wu1_bot
#define OFF_BFRG (OFF_D2 + 64)             // 4*64 uint4 = 1024 dwords
#define OFF_BSUM (OFF_BFRG + 1024)         // 128 block sums (scan)
#define OFF_BOFF (OFF_BSUM + 128)          // 128 block offsets (scan)
#define OFF_PRA  (OFF_BOFF + 128)          // NN*64 f32 (fallback path)
#define OFF_PRAH (OFF_PRA + NN * 64)       // NN*32: PRA in bf16 (64/row)
#define OFF_PRU  (OFF_PRAH + NN * 32)      // NN*64
#define OFF_H    (OFF_PRU + NN * 64)       // NN*64  (agg in fallback)
#define OFF_HIST (OFF_H + NN * 64)         // NN
#define OFF_CUR  (OFF_HIST + NN)           // NN
#define OFF_STRT (OFF_CUR + NN)            // NN+1 (+pad)
#define OFF_HS   (OFF_STRT + NN + 4)       // NE*64 bf16 = NE*32 dwords
#define WS_UNITS (OFF_HS + NE * 32)

__device__ __forceinline__ unsigned bfr(float x) {
  unsigned u = __float_as_uint(x);
  return (u + 0x7fffu + ((u >> 16) & 1u)) >> 16;
}
__device__ __forceinline__ float bf2f(unsigned short h) {
  return __uint_as_float(((unsigned)h) << 16);
}
// add two bf16x2-packed uints, relu, repack
__device__ __forceinline__ unsigned addrelu1(unsigned qa, unsigned pb) {
  float lo = __uint_as_float((qa & 0xffffu) << 16) +
             __uint_as_float((pb & 0xffffu) << 16);
  float hi = __uint_as_float(qa & 0xffff0000u) +
             __uint_as_float(pb & 0xffff0000u);
  lo = fmaxf(lo, 0.f);
  hi = fmaxf(hi, 0.f);
  return bfr(lo) | (bfr(hi) << 16);
}
__device__ __forceinline__ uint4 addrelu4(uint4 q, uint4 p) {
  return make_uint4(addrelu1(q.x, p.x), addrelu1(q.y, p.y),
                    addrelu1(q.z, p.z), addrelu1(q.w, p.w));
}

// ---------------------------------------------------------------------------
// Weight folding + bf16 B-fragment pack for MFMA (same as round 12)
// ---------------------------------------------------------------------------
__global__ __launch_bounds__(256) void k_fold(
    const float* __restrict__ wn, const float* __restrict__ bn,
    const float* __restrict__ we, const float* __restrict__ be,
    const float* __restrict__ wm1, const float* __restrict__ bm1,
    const float* __restrict__ wm2, const float* __restrict__ bm2,
    const float* __restrict__ wu1,
    float* __restrict__ M, float* __restrict__ B, float* __restrict__ c,
    float* __restrict__ W2U, float* __restrict__ d2,
    uint4* __restrict__ Bfrag) {
  int t = blockIdx.x * 256 + threadIdx.x;
  if (t < 16384) {
    int k = t >> 7, j = t & 127;
    float acc;
    if (j < 64) {
      acc = 0.f;
      for (int h = 0; h < 64; ++h) acc += wn[k * 64 + h] * wm1[h * 64 + j];
    } else {
      acc = wu1[k * 64 + (j - 64)];
    }
    M[t] = acc;
  } else if (t < 16384 + 2048) {
    int u = t - 16384;
    int k = u >> 6, j = u & 63;
    float acc = 0.f;
    for (int h = 0; h < 64; ++h) acc += we[k * 64 + h] * wm1[(64 + h) * 64 + j];
    B[u] = acc;
  } else if (t < 16384 + 2048 + 64) {
    int j = t - (16384 + 2048);
    float acc = bm1[j];
    for (int h = 0; h < 64; ++h)
      acc += bn[h] * wm1[h * 64 + j] + be[h] * wm1[(64 + h) * 64 + j];
    c[j] = acc;
  } else if (t < 16384 + 2048 + 64 + 4096) {
    int u = t - (16384 + 2048 + 64);
    int k = u >> 6, j = u & 63;
    float acc = 0.f;
    for (int h = 0; h < 64; ++h) acc += wm2[k * 64 + h] * wu1[(128 + h) * 64 + j];
    W2U[u] = acc;
  } else if (t < 16384 + 2048 + 64 + 4096 + 64) {
    int j = t - (16384 + 2048 + 64 + 4096);
    float acc = 0.f;
    for (int h = 0; h < 64; ++h) acc += bm2[h] * wu1[(128 + h) * 64 + j];
    d2[j] = acc;
  } else if (t < 16384 + 2048 + 64 + 4096 + 64 + 256) {
    int u = t - (16384 + 2048 + 64 + 4096 + 64);
    int jb = u >> 6, l = u & 63;
    int g = l >> 4, n = l & 15;
    unsigned s[8];
#pragma unroll
    for (int i = 0; i < 8; ++i) {
      int k = g * 8 + i;
      int j = jb * 16 + n;
      float acc = 0.f;
      for (int h = 0; h < 64; ++h)
        acc += we[k * 64 + h] * wm1[(64 + h) * 64 + j];
      s[i] = bfr(acc);
    }
    Bfrag[jb * 64 + l] = make_uint4(s[0] | (s[1] << 16), s[2] | (s[3] << 16),
                                    s[4] | (s[5] << 16), s[6] | (s[7] << 16));
  }
}

// ---------------------------------------------------------------------------
// PRA[n] = nf[n]@A (f32 + bf16 copy) ; PRU[n] = nf[n]@wu1_top
// ---------------------------------------------------------------------------
__global__ __launch_bounds__(256) void k_node(
    const float* __restrict__ nf, const float* __restrict__ M,
    float* __restrict__ PRA, unsigned* __restrict__ PRAh,
    float* __restrict__ PRU) {
  int n = blockIdx.x * 256 + threadIdx.x;
  if (n >= NN) return;
  const float* __restrict__ row = &nf[(size_t)n * 128];
#pragma unroll 1
  for (int jc = 0; jc < 128; jc += 32) {
    float q[32];
#pragma unroll
    for (int jj = 0; jj < 32; ++jj) q[jj] = 0.f;
#pragma unroll 4
    for (int k = 0; k < 128; k += 4) {
      float4 r4 = *(const float4*)&row[k];
#pragma unroll
      for (int jj = 0; jj < 32; ++jj) q[jj] += r4.x * M[(k + 0) * 128 + jc + jj];
#pragma unroll
      for (int jj = 0; jj < 32; ++jj) q[jj] += r4.y * M[(k + 1) * 128 + jc + jj];
#pragma unroll
      for (int jj = 0; jj < 32; ++jj) q[jj] += r4.z * M[(k + 2) * 128 + jc + jj];
#pragma unroll
      for (int jj = 0; jj < 32; ++jj) q[jj] += r4.w * M[(k + 3) * 128 + jc + jj];
    }
    float* dstp = (jc < 64) ? &PRA[(size_t)n * 64 + jc] : &PRU[(size_t)n * 64 + (jc - 64)];
#pragma unroll
    for (int jj = 0; jj < 32; jj += 4)
      *(float4*)&dstp[jj] = make_float4(q[jj], q[jj + 1], q[jj + 2], q[jj + 3]);
    if (jc < 64) {  // bf16 copy for the fused message kernel
      unsigned w[16];
#pragma unroll
      for (int jj = 0; jj < 32; jj += 2)
        w[jj / 2] = bfr(q[jj]) | (bfr(q[jj + 1]) << 16);
      unsigned* hp = &PRAh[(size_t)n * 32 + jc / 2];
#pragma unroll
      for (int u = 0; u < 4; ++u)
        *(uint4*)&hp[4 * u] = make_uint4(w[4 * u], w[4 * u + 1], w[4 * u + 2], w[4 * u + 3]);
    }
  }
}

// ---------------------------------------------------------------------------
// Counting sort: hist -> 3-phase scan
// ---------------------------------------------------------------------------
__global__ __launch_bounds__(256) void k_hist(const int* __restrict__ idx,
                                              int* __restrict__ hist) {
  int e = blockIdx.x * 256 + threadIdx.x;
  if (e < NE) atomicAdd(&hist[idx[NE + e]], 1);
}

__global__ __launch_bounds__(1024) void k_scanA(const int* __restrict__ hist,
                                                int* __restrict__ strt,
                                                int* __restrict__ bsum) {
  __shared__ int lds[1024];
  int t = threadIdx.x;
  int i = blockIdx.x * 1024 + t;
  int v = (i < NN) ? hist[i] : 0;
  lds[t] = v;
  __syncthreads();
  for (int off = 1; off < 1024; off <<= 1) {
    int u = (t >= off) ? lds[t - off] : 0;
    __syncthreads();
    lds[t] += u;
    __syncthreads();
  }
  if (i < NN) strt[i] = lds[t] - v;
  if (t == 1023) bsum[blockIdx.x] = lds[1023];
}

__global__ __launch_bounds__(128) void k_scanB(const int* __restrict__ bsum,
                                               int* __restrict__ boff,
                                               int* __restrict__ strt,
                                               int nblocks) {
  __shared__ int lds[128];
  int t = threadIdx.x;
  int v = (t < nblocks) ? bsum[t] : 0;
  lds[t] = v;
  __syncthreads();
  for (int off = 1; off < 128; off <<= 1) {
    int u = (t >= off) ? lds[t - off] : 0;
    __syncthreads();
    lds[t] += u;
    __syncthreads();
  }
  if (t < nblocks) boff[t] = lds[t] - v;
  if (t == 127) strt[NN] = lds[127];
}

__global__ __launch_bounds__(1024) void k_scanC(int* __restrict__ strt,
                                                const int* __restrict__ boff) {
  int i = blockIdx.x * 1024 + threadIdx.x;
  if (i < NN) strt[i] += boff[blockIdx.x];
}

// ---------------------------------------------------------------------------
// k_msgh: one WAVE per tile of 16 consecutive edges (edge order).
//   MFMA computes q = ef@B (4x mfma_f32_16x16x32_bf16), + bias -> LDS
//   transpose; then 4-lane groups add PRAh[src] (bf16), relu, and store the
//   activated h row as one 128B burst to its dst-sorted slot.
//   No srcS, no per-slot 4B scatter.
// ---------------------------------------------------------------------------
__global__ __launch_bounds__(256) void k_msgh(
    const int* __restrict__ idx, const int* __restrict__ strt,
    int* __restrict__ cursor, const float* __restrict__ ef,
    const uint4* __restrict__ Bfrag, const float* __restrict__ c,
    const uint4* __restrict__ PRAh, unsigned short* __restrict__ hS) {
  __shared__ unsigned short ldsQ[4][16 * 72];  // row stride 72 shorts = 144B
  __shared__ int slotA[4][16];
  __shared__ int srcA[4][16];
  int wib = threadIdx.x >> 6;
  int lane = threadIdx.x & 63;
  int m = lane & 15, g = lane >> 4;
  int tile = blockIdx.x * 4 + wib;

  // phase 1: slot assignment (one lane per edge); keep slot+src in LDS
  if (lane < 16) {
    int e = tile * 16 + m;
    int src = idx[e];
    int dst = idx[NE + e];
    int pos = atomicAdd(&cursor[dst], 1);
    slotA[wib][m] = strt[dst] + pos;
    srcA[wib][m] = src;
  }

  // phase 2: A fragment (edge m, k = g*8 .. g*8+7)
  const float* __restrict__ rp = &ef[(size_t)(tile * 16 + m) * 32 + g * 8];
  float4 f0 = *(const float4*)rp;
  float4 f1 = *(const float4*)(rp + 4);
  bf16x8 a;
  a[0] = (short)bfr(f0.x); a[1] = (short)bfr(f0.y);
  a[2] = (short)bfr(f0.z); a[3] = (short)bfr(f0.w);
  a[4] = (short)bfr(f1.x); a[5] = (short)bfr(f1.y);
  a[6] = (short)bfr(f1.z); a[7] = (short)bfr(f1.w);

  // phase 3: B fragments (coalesced 16B/lane) + per-lane bias
  const bf16x8* __restrict__ bfp = (const bf16x8*)Bfrag;
  bf16x8 b0 = bfp[0 * 64 + lane];
  bf16x8 b1 = bfp[1 * 64 + lane];
  bf16x8 b2 = bfp[2 * 64 + lane];
  bf16x8 b3 = bfp[3 * 64 + lane];
  float cl0 = c[0 * 16 + m], cl1 = c[1 * 16 + m];
  float cl2 = c[2 * 16 + m], cl3 = c[3 * 16 + m];

  // phase 4: MFMA (Q = EF @ B per 16-col block)
  f32x4 z = {0.f, 0.f, 0.f, 0.f};
  f32x4 q0 = __builtin_amdgcn_mfma_f32_16x16x32_bf16(a, b0, z, 0, 0, 0);
  f32x4 q1 = __builtin_amdgcn_mfma_f32_16x16x32_bf16(a, b1, z, 0, 0, 0);
  f32x4 q2 = __builtin_amdgcn_mfma_f32_16x16x32_bf16(a, b2, z, 0, 0, 0);
  f32x4 q3 = __builtin_amdgcn_mfma_f32_16x16x32_bf16(a, b3, z, 0, 0, 0);

  // phase 5: + bias, cvt bf16, write LDS (row = g*4+r, col = jb*16+m)
  unsigned short* __restrict__ lq = &ldsQ[wib][0];
#pragma unroll
  for (int r = 0; r < 4; ++r) {
    int mp = g * 4 + r;
    lq[mp * 72 + 0 * 16 + m] = (unsigned short)bfr(q0[r] + cl0);
    lq[mp * 72 + 1 * 16 + m] = (unsigned short)bfr(q1[r] + cl1);
    lq[mp * 72 + 2 * 16 + m] = (unsigned short)bfr(q2[r] + cl2);
    lq[mp * 72 + 3 * 16 + m] = (unsigned short)bfr(q3[r] + cl3);
  }
  __syncthreads();

  // phase 6: 4 lanes per edge: read q halves, add PRAh[src] (bf16), relu,
  // store the 128B h row as one burst
  int m2 = lane >> 2, lo = lane & 3;
  uint4 w0 = *(const uint4*)&ldsQ[wib][m2 * 72 + lo * 16];
  uint4 w1 = *(const uint4*)&ldsQ[wib][m2 * 72 + lo * 16 + 8];
  int slot = slotA[wib][m2];
  int src = srcA[wib][m2];
  uint4 p0 = PRAh[(size_t)src * 8 + lo * 2];
  uint4 p1 = PRAh[(size_t)src * 8 + lo * 2 + 1];
  uint4 h0 = addrelu4(w0, p0);
  uint4 h1 = addrelu4(w1, p1);
  uint4* __restrict__ qp = (uint4*)(hS + (size_t)slot * 64);
  qp[lo * 2] = h0;
  qp[lo * 2 + 1] = h1;
}

// ---------------------------------------------------------------------------
// k_sum: pure streaming segment-sum of contiguous dst-sorted h rows.
// Wave per node, lane = dim; rows are 128B coalesced; zero indirection.
// ---------------------------------------------------------------------------
__global__ __launch_bounds__(256) void k_sum(
    const unsigned short* __restrict__ hS, const int* __restrict__ strt,
    float* __restrict__ H) {
  int wib = threadIdx.x >> 6;
  int lane = threadIdx.x & 63;
  int n = blockIdx.x * 4 + wib;
  if (n >= NN) return;
  int s0 = strt[n], s1 = strt[n + 1];
  float acc = 0.f;
  int s = s0;
  for (; s + 4 <= s1; s += 4) {
    unsigned short a0 = hS[(size_t)(s + 0) * 64 + lane];
    unsigned short a1 = hS[(size_t)(s + 1) * 64 + lane];
    unsigned short a2 = hS[(size_t)(s + 2) * 64 + lane];
    unsigned short a3 = hS[(size_t)(s + 3) * 64 + lane];
    acc += (bf2f(a0) + bf2f(a1)) + (bf2f(a2) + bf2f(a3));
  }
  for (; s < s1; ++s) acc += bf2f(hS[(size_t)s * 64 + lane]);
  H[(size_t)n * 64 + lane] = acc;
}

// ---------------------------------------------------------------------------
// Final per-node MLP with W2U fold:
//   pre = PRU[n] + H[n]@W2U + deg*d2 + bu1 ; out = relu(pre)@wu2 + bu2
// ---------------------------------------------------------------------------
__global__ __launch_bounds__(256) void k_update3(
    const float* __restrict__ H, const int* __restrict__ strt,
    const float* __restrict__ PRU,
    const float* __restrict__ W2U, const float* __restrict__ d2,
    const float* __restrict__ bu1,
    const float* __restrict__ wu2, const float* __restrict__ bu2,
    float* __restrict__ out) {
  int n = blockIdx.x * 256 + threadIdx.x;
  if (n >= NN) return;

  float Hr[64];
#pragma unroll
  for (int k = 0; k < 64; k += 4)
    *(float4*)&Hr[k] = *(const float4*)&H[(size_t)n * 64 + k];
  float deg = (float)(strt[n + 1] - strt[n]);

  float acc[64];
#pragma unroll
  for (int o = 0; o < 64; ++o) acc[o] = bu2[o];

  const float* __restrict__ prs = &PRU[(size_t)n * 64];
#pragma unroll 1
  for (int jc = 0; jc < 64; jc += 16) {
    float q[16];
#pragma unroll
    for (int jj = 0; jj < 16; ++jj) q[jj] = bu1[jc + jj] + deg * d2[jc + jj];
#pragma unroll
    for (int k = 0; k < 64; ++k) {
      float hv = Hr[k];
#pragma unroll
      for (int jj = 0; jj < 16; ++jj) q[jj] += hv * W2U[k * 64 + jc + jj];
    }
#pragma unroll
    for (int jj = 0; jj < 16; ++jj) {
      float h = fmaxf(prs[jc + jj] + q[jj], 0.f);
#pragma unroll
      for (int o = 0; o < 64; ++o) acc[o] += h * wu2[(jc + jj) * 64 + o];
    }
  }

#pragma unroll
  for (int o = 0; o < 64; o += 4)
    *(float4*)&out[(size_t)n * 64 + o] = make_float4(acc[o], acc[o + 1], acc[o + 2], acc[o + 3]);
}

// ---------------------------------------------------------------------------
// Fallback (ws too small): round-1 atomic scatter path
// ---------------------------------------------------------------------------
__global__ __launch_bounds__(256) void k_edge_at(
    const int* __restrict__ idx, const float* __restrict__ ef,
    const float* __restrict__ B, const float* __restrict__ c,
    const float* __restrict__ wm2, const float* __restrict__ bm2,
    const float* __restrict__ PRA, float* __restrict__ agg) {
  int e = blockIdx.x * 256 + threadIdx.x;
  if (e >= NE) return;
  int src = idx[e];
  int dst = idx[NE + e];
  float efr[32];
#pragma unroll
  for (int k = 0; k < 32; k += 4)
    *(float4*)&efr[k] = *(const float4*)&ef[(size_t)e * 32 + k];
  float m[64];
#pragma unroll
  for (int o = 0; o < 64; ++o) m[o] = bm2[o];
  const float* __restrict__ prs = &PRA[(size_t)src * 64];
#pragma unroll 1
  for (int jc = 0; jc < 64; jc += 16) {
    float q[16];
#pragma unroll
    for (int jj = 0; jj < 16; ++jj) q[jj] = c[jc + jj];
#pragma unroll
    for (int k = 0; k < 32; ++k) {
      float ev = efr[k];
#pragma unroll
      for (int jj = 0; jj < 16; ++jj) q[jj] += ev * B[k * 64 + jc + jj];
    }
#pragma unroll
    for (int jj = 0; jj < 16; ++jj) {
      float h = fmaxf(prs[jc + jj] + q[jj], 0.f);
#pragma unroll
      for (int o = 0; o < 64; ++o) m[o] += h * wm2[(jc + jj) * 64 + o];
    }
  }
  float* __restrict__ ap = &agg[(size_t)dst * 64];
#pragma unroll
  for (int o = 0; o < 64; ++o) atomicAdd(&ap[o], m[o]);
}

__global__ __launch_bounds__(256) void k_update_at(
    const float* __restrict__ agg, const float* __restrict__ PRU,
    const float* __restrict__ wu1, const float* __restrict__ bu1,
    const float* __restrict__ wu2, const float* __restrict__ bu2,
    float* __restrict__ out) {
  int n = blockIdx.x * 256 + threadIdx.x;
  if (n >= NN) return;
  float ar[64];
#pragma unroll
  for (int k = 0; k < 64; k += 4)
    *(float4*)&ar[k] = *(const float4*)&agg[(size_t)n * 64 + k];
  float acc[64];
#pragma unroll
  for (int o = 0; o < 64; ++o) acc[o] = bu2[o];
  const float* __restrict__ prs = &PRU[(size_t)n * 64];
#pragma unroll 1
  for (int jc = 0; jc < 64; jc += 16) {
    float q[16];
#pragma unroll
    for (int jj = 0; jj < 16; ++jj) q[jj] = bu1[jc + jj];
#pragma unroll
    for (int k = 0; k < 64; ++k) {
      float av = ar[k];
#pragma unroll
      for (int jj = 0; jj < 16; ++jj) q[jj] += av * wu1[(128 + k) * 64 + jc + jj];
    }
#pragma unroll
    for (int jj = 0; jj < 16; ++jj) {
      float h = fmaxf(prs[jc + jj] + q[jj], 0.f);
#pragma unroll
      for (int o = 0; o < 64; ++o) acc[o] += h * wu2[(jc + jj) * 64 + o];
    }
  }
#pragma unroll
  for (int o = 0; o < 64; o += 4)
    *(float4*)&out[(size_t)n * 64 + o] = make_float4(acc[o], acc[o + 1], acc[o + 2], acc[o + 3]);
}

extern "C" void kernel_launch(void* const* d_in, const int* in_sizes, int n_in,
                              void* d_out, int out_size, void* d_ws, size_t ws_size,
                              hipStream_t stream) {
  const float* nf  = (const float*)d_in[0];
  const int*   idx = (const int*)d_in[1];
  const float* ef  = (const float*)d_in[2];
  const float* wn  = (const float*)d_in[3];
  const float* bn  = (const float*)d_in[4];
  const float* we  = (const float*)d_in[5];
  const float* be  = (const float*)d_in[6];
  const float* wm1 = (const float*)d_in[7];
  const float* bm1 = (const float*)d_in[8];
  const float* wm2 = (const float*)d_in[9];
  const float* bm2 = (const float*)d_in[10];
  const float* wu1 = (const float*)d_in[11];
  const float* bu1 = (const float*)d_in[12];
  const float* wu2 = (const float*)d_in[13];
  const float* bu2 = (const float*)d_in[14];
  float* out = (float*)d_out;

  float* ws   = (float*)d_ws;
  float* M    = ws + OFF_M;
  float* B    = ws + OFF_B;
  float* c    = ws + OFF_C;
  float* W2U  = ws + OFF_W2U;
  float* d2   = ws + OFF_D2;
  uint4* Bfrg = (uint4*)(ws + OFF_BFRG);
  int*   bsum = (int*)(ws + OFF_BSUM);
  int*   boff = (int*)(ws + OFF_BOFF);
  float* PRA  = ws + OFF_PRA;
  unsigned* PRAh = (unsigned*)(ws + OFF_PRAH);
  float* PRU  = ws + OFF_PRU;
  float* H    = ws + OFF_H;
  int*   hist = (int*)(ws + OFF_HIST);
  int*   cur  = (int*)(ws + OFF_CUR);
  int*   strt = (int*)(ws + OFF_STRT);
  unsigned short* hS = (unsigned short*)(ws + OFF_HS);

  const int SCAN_BLOCKS = (NN + 1023) / 1024;  // 98
  const int FOLD_THREADS = 16384 + 2048 + 64 + 4096 + 64 + 256;

  k_fold<<<(FOLD_THREADS + 255) / 256, 256, 0, stream>>>(
      wn, bn, we, be, wm1, bm1, wm2, bm2, wu1, M, B, c, W2U, d2, Bfrg);
  k_node<<<(NN + 255) / 256, 256, 0, stream>>>(nf, M, PRA, PRAh, PRU);

  if (ws_size >= (size_t)WS_UNITS * 4) {
    hipMemsetAsync(hist, 0, (size_t)2 * NN * sizeof(int), stream);
    k_hist<<<(NE + 255) / 256, 256, 0, stream>>>(idx, hist);
    k_scanA<<<SCAN_BLOCKS, 1024, 0, stream>>>(hist, strt, bsum);
    k_scanB<<<1, 128, 0, stream>>>(bsum, boff, strt, SCAN_BLOCKS);
    k_scanC<<<SCAN_BLOCKS, 1024, 0, stream>>>(strt, boff);
    k_msgh<<<NE / 16 / 4, 256, 0, stream>>>(idx, strt, cur, ef, Bfrg, c,
                                            (const uint4*)PRAh, hS);
    k_sum<<<(NN + 3) / 4, 256, 0, stream>>>(hS, strt, H);
    k_update3<<<(NN + 255) / 256, 256, 0, stream>>>(
        H, strt, PRU, W2U, d2, bu1, wu2, bu2, out);
  } else {
    hipMemsetAsync(H, 0, (size_t)NN * 64 * sizeof(float), stream);
    k_edge_at<<<(NE + 255) / 256, 256, 0, stream>>>(idx, ef, B, c, wm2, bm2, PRA, H);
    k_update_at<<<(NN + 255) / 256, 256, 0, stream>>>(
        H, PRU, wu1, bu1, wu2, bu2, out);
  }
}

// Round 15
// 600.476 us; speedup vs baseline: 1.0931x; 1.0931x over previous
//
#include <hip/hip_runtime.h>

#define NN 100000
#define NE 1600000

typedef __attribute__((ext_vector_type(8))) short bf16x8;
typedef __attribute__((ext_vector_type(4))) float f32x4;

// ---------------------------------------------------------------------------
// Workspace layout in 4-byte units (~296 MB; round-5 tier-1 proved >=494 MB)
// ---------------------------------------------------------------------------
#define OFF_M    0                         // 128*128 folded [A | wu1_top] (fallback)
#define OFF_B    (OFF_M + 16384)           // 32*64   we @ wm1_bot (fp32, fallback)
#define OFF_C    (OFF_B + 2048)            // 64      folded msg bias
#define OFF_W2U  (OFF_C + 64)              // 64*64   wm2 @ wu1_bot
#define OFF_D2   (OFF_W2U + 4096)          // 64      bm2 @ wu1_bot
#define OFF_BFRG (OFF_D2 + 64)             // 4*64 uint4 = 1024 dwords
#define OFF_MFRG (OFF_BFRG + 1024)         // 8 jb * 4 kb * 64 lanes uint4 = 8192 dwords
#define OFF_BSUM (OFF_MFRG + 8192)         // 128 block sums (scan)
#define OFF_BOFF (OFF_BSUM + 128)          // 128 block offsets (scan)
#define OFF_PRA  (OFF_BOFF + 128)          // NN*64 f32
#define OFF_PRAH (OFF_PRA + NN * 64)       // NN*32: PRA in bf16 (64/row)
#define OFF_PRU  (OFF_PRAH + NN * 32)      // NN*64
#define OFF_H    (OFF_PRU + NN * 64)       // NN*64  (agg in fallback)
#define OFF_HIST (OFF_H + NN * 64)         // NN
#define OFF_CUR  (OFF_HIST + NN)           // NN
#define OFF_STRT (OFF_CUR + NN)            // NN+1 (+pad)
#define OFF_HS   (OFF_STRT + NN + 4)       // NE*64 bf16 = NE*32 dwords
#define WS_UNITS (OFF_HS + NE * 32)

__device__ __forceinline__ unsigned bfr(float x) {
  unsigned u = __float_as_uint(x);
  return (u + 0x7fffu + ((u >> 16) & 1u)) >> 16;
}
__device__ __forceinline__ float bf2f(unsigned short h) {
  return __uint_as_float(((unsigned)h) << 16);
}
__device__ __forceinline__ unsigned addrelu1(unsigned qa, unsigned pb) {
  float lo = __uint_as_float((qa & 0xffffu) << 16) +
             __uint_as_float((pb & 0xffffu) << 16);
  float hi = __uint_as_float(qa & 0xffff0000u) +
             __uint_as_float(pb & 0xffff0000u);
  lo = fmaxf(lo, 0.f);
  hi = fmaxf(hi, 0.f);
  return bfr(lo) | (bfr(hi) << 16);
}
__device__ __forceinline__ uint4 addrelu4(uint4 q, uint4 p) {
  return make_uint4(addrelu1(q.x, p.x), addrelu1(q.y, p.y),
                    addrelu1(q.z, p.z), addrelu1(q.w, p.w));
}

// ---------------------------------------------------------------------------
// Weight folding + bf16 fragment packs:
//   M[128][128]: cols 0-63 = wn@wm1_top ; cols 64-127 = wu1[0:128,:]
//   B[32][64] = we@wm1_bot ; c = bm1 + bn@wm1_top + be@wm1_bot
//   W2U = wm2@wu1_bot ; d2 = bm2@wu1_bot
//   Bfrag[jb][l] : B bf16 frags (msg MFMA)
//   Mfrag[jb][kb][l] : M bf16 frags (node MFMA), row=kb*32+(l>>4)*8+i,
//                      col=jb*16+(l&15)
// ---------------------------------------------------------------------------
__global__ __launch_bounds__(256) void k_fold(
    const float* __restrict__ wn, const float* __restrict__ bn,
    const float* __restrict__ we, const float* __restrict__ be,
    const float* __restrict__ wm1, const float* __restrict__ bm1,
    const float* __restrict__ wm2, const float* __restrict__ bm2,
    const float* __restrict__ wu1,
    float* __restrict__ M, float* __restrict__ B, float* __restrict__ c,
    float* __restrict__ W2U, float* __restrict__ d2,
    uint4* __restrict__ Bfrag, uint4* __restrict__ Mfrag) {
  int t = blockIdx.x * 256 + threadIdx.x;
  if (t < 16384) {
    int k = t >> 7, j = t & 127;
    float acc;
    if (j < 64) {
      acc = 0.f;
      for (int h = 0; h < 64; ++h) acc += wn[k * 64 + h] * wm1[h * 64 + j];
    } else {
      acc = wu1[k * 64 + (j - 64)];
    }
    M[t] = acc;
  } else if (t < 16384 + 2048) {
    int u = t - 16384;
    int k = u >> 6, j = u & 63;
    float acc = 0.f;
    for (int h = 0; h < 64; ++h) acc += we[k * 64 + h] * wm1[(64 + h) * 64 + j];
    B[u] = acc;
  } else if (t < 16384 + 2048 + 64) {
    int j = t - (16384 + 2048);
    float acc = bm1[j];
    for (int h = 0; h < 64; ++h)
      acc += bn[h] * wm1[h * 64 + j] + be[h] * wm1[(64 + h) * 64 + j];
    c[j] = acc;
  } else if (t < 16384 + 2048 + 64 + 4096) {
    int u = t - (16384 + 2048 + 64);
    int k = u >> 6, j = u & 63;
    float acc = 0.f;
    for (int h = 0; h < 64; ++h) acc += wm2[k * 64 + h] * wu1[(128 + h) * 64 + j];
    W2U[u] = acc;
  } else if (t < 16384 + 2048 + 64 + 4096 + 64) {
    int j = t - (16384 + 2048 + 64 + 4096);
    float acc = 0.f;
    for (int h = 0; h < 64; ++h) acc += bm2[h] * wu1[(128 + h) * 64 + j];
    d2[j] = acc;
  } else if (t < 16384 + 2048 + 64 + 4096 + 64 + 256) {
    int u = t - (16384 + 2048 + 64 + 4096 + 64);
    int jb = u >> 6, l = u & 63;
    int g = l >> 4, n = l & 15;
    unsigned s[8];
#pragma unroll
    for (int i = 0; i < 8; ++i) {
      int k = g * 8 + i;
      int j = jb * 16 + n;
      float acc = 0.f;
      for (int h = 0; h < 64; ++h)
        acc += we[k * 64 + h] * wm1[(64 + h) * 64 + j];
      s[i] = bfr(acc);
    }
    Bfrag[jb * 64 + l] = make_uint4(s[0] | (s[1] << 16), s[2] | (s[3] << 16),
                                    s[4] | (s[5] << 16), s[6] | (s[7] << 16));
  } else if (t < 16384 + 2048 + 64 + 4096 + 64 + 256 + 2048) {
    int u = t - (16384 + 2048 + 64 + 4096 + 64 + 256);
    int jb = u >> 8, kb = (u >> 6) & 3, l = u & 63;
    int g = l >> 4, n = l & 15;
    int j = jb * 16 + n;
    unsigned s[8];
#pragma unroll
    for (int i = 0; i < 8; ++i) {
      int k = kb * 32 + g * 8 + i;
      float acc;
      if (j < 64) {
        acc = 0.f;
        for (int h = 0; h < 64; ++h) acc += wn[k * 64 + h] * wm1[h * 64 + j];
      } else {
        acc = wu1[k * 64 + (j - 64)];
      }
      s[i] = bfr(acc);
    }
    Mfrag[(jb * 4 + kb) * 64 + l] =
        make_uint4(s[0] | (s[1] << 16), s[2] | (s[3] << 16),
                   s[4] | (s[5] << 16), s[6] | (s[7] << 16));
  }
}

// ---------------------------------------------------------------------------
// k_node2: MFMA node precompute. Wave per 16-node tile; K=128 via 4 chained
// mfma_f32_16x16x32_bf16 per 16-col block; jb 0-3 -> PRA, jb 4-7 -> PRU.
// D layout (proven in msgq3): lane l holds rows (l>>4)*4+r, col jb*16+(l&15).
// ---------------------------------------------------------------------------
__global__ __launch_bounds__(256) void k_node2(
    const float* __restrict__ nf, const uint4* __restrict__ Mfrag,
    float* __restrict__ PRA, float* __restrict__ PRU) {
  int wib = threadIdx.x >> 6;
  int lane = threadIdx.x & 63;
  int tile = blockIdx.x * 4 + wib;
  if (tile >= NN / 16) return;  // NN = 6250*16 exactly
  int m = lane & 15, g = lane >> 4;
  int node = tile * 16 + m;

  bf16x8 a[4];
#pragma unroll
  for (int kb = 0; kb < 4; ++kb) {
    const float* __restrict__ rp = &nf[(size_t)node * 128 + kb * 32 + g * 8];
    float4 f0 = *(const float4*)rp;
    float4 f1 = *(const float4*)(rp + 4);
    bf16x8 v;
    v[0] = (short)bfr(f0.x); v[1] = (short)bfr(f0.y);
    v[2] = (short)bfr(f0.z); v[3] = (short)bfr(f0.w);
    v[4] = (short)bfr(f1.x); v[5] = (short)bfr(f1.y);
    v[6] = (short)bfr(f1.z); v[7] = (short)bfr(f1.w);
    a[kb] = v;
  }

  const bf16x8* __restrict__ mfp = (const bf16x8*)Mfrag;
#pragma unroll
  for (int jb = 0; jb < 8; ++jb) {
    f32x4 acc = {0.f, 0.f, 0.f, 0.f};
    acc = __builtin_amdgcn_mfma_f32_16x16x32_bf16(a[0], mfp[(jb * 4 + 0) * 64 + lane], acc, 0, 0, 0);
    acc = __builtin_amdgcn_mfma_f32_16x16x32_bf16(a[1], mfp[(jb * 4 + 1) * 64 + lane], acc, 0, 0, 0);
    acc = __builtin_amdgcn_mfma_f32_16x16x32_bf16(a[2], mfp[(jb * 4 + 2) * 64 + lane], acc, 0, 0, 0);
    acc = __builtin_amdgcn_mfma_f32_16x16x32_bf16(a[3], mfp[(jb * 4 + 3) * 64 + lane], acc, 0, 0, 0);
    float* __restrict__ dst = (jb < 4) ? PRA : PRU;
    int col = (jb & 3) * 16 + m;
#pragma unroll
    for (int r = 0; r < 4; ++r) {
      int row = tile * 16 + g * 4 + r;
      dst[(size_t)row * 64 + col] = acc[r];
    }
  }
}

// PRAh pack: coalesced f32 pairs -> bf16x2
__global__ __launch_bounds__(256) void k_prah(
    const float2* __restrict__ PRA2, unsigned* __restrict__ PRAh) {
  int t = blockIdx.x * 256 + threadIdx.x;
  if (t < NN * 32) {
    float2 v = PRA2[t];
    PRAh[t] = bfr(v.x) | (bfr(v.y) << 16);
  }
}

// ---------------------------------------------------------------------------
// Counting sort: hist -> 3-phase scan
// ---------------------------------------------------------------------------
__global__ __launch_bounds__(256) void k_hist(const int* __restrict__ idx,
                                              int* __restrict__ hist) {
  int e = blockIdx.x * 256 + threadIdx.x;
  if (e < NE) atomicAdd(&hist[idx[NE + e]], 1);
}

__global__ __launch_bounds__(1024) void k_scanA(const int* __restrict__ hist,
                                                int* __restrict__ strt,
                                                int* __restrict__ bsum) {
  __shared__ int lds[1024];
  int t = threadIdx.x;
  int i = blockIdx.x * 1024 + t;
  int v = (i < NN) ? hist[i] : 0;
  lds[t] = v;
  __syncthreads();
  for (int off = 1; off < 1024; off <<= 1) {
    int u = (t >= off) ? lds[t - off] : 0;
    __syncthreads();
    lds[t] += u;
    __syncthreads();
  }
  if (i < NN) strt[i] = lds[t] - v;
  if (t == 1023) bsum[blockIdx.x] = lds[1023];
}

__global__ __launch_bounds__(128) void k_scanB(const int* __restrict__ bsum,
                                               int* __restrict__ boff,
                                               int* __restrict__ strt,
                                               int nblocks) {
  __shared__ int lds[128];
  int t = threadIdx.x;
  int v = (t < nblocks) ? bsum[t] : 0;
  lds[t] = v;
  __syncthreads();
  for (int off = 1; off < 128; off <<= 1) {
    int u = (t >= off) ? lds[t - off] : 0;
    __syncthreads();
    lds[t] += u;
    __syncthreads();
  }
  if (t < nblocks) boff[t] = lds[t] - v;
  if (t == 127) strt[NN] = lds[127];
}

__global__ __launch_bounds__(1024) void k_scanC(int* __restrict__ strt,
                                                const int* __restrict__ boff) {
  int i = blockIdx.x * 1024 + threadIdx.x;
  if (i < NN) strt[i] += boff[blockIdx.x];
}

// ---------------------------------------------------------------------------
// k_msgh: wave per 16-edge tile; MFMA q=ef@B + bias -> LDS transpose ->
// add PRAh[src] (bf16), relu, one 128B burst per edge to dst-sorted slot.
// ---------------------------------------------------------------------------
__global__ __launch_bounds__(256) void k_msgh(
    const int* __restrict__ idx, const int* __restrict__ strt,
    int* __restrict__ cursor, const float* __restrict__ ef,
    const uint4* __restrict__ Bfrag, const float* __restrict__ c,
    const uint4* __restrict__ PRAh, unsigned short* __restrict__ hS) {
  __shared__ unsigned short ldsQ[4][16 * 72];
  __shared__ int slotA[4][16];
  __shared__ int srcA[4][16];
  int wib = threadIdx.x >> 6;
  int lane = threadIdx.x & 63;
  int m = lane & 15, g = lane >> 4;
  int tile = blockIdx.x * 4 + wib;

  if (lane < 16) {
    int e = tile * 16 + m;
    int src = idx[e];
    int dst = idx[NE + e];
    int pos = atomicAdd(&cursor[dst], 1);
    slotA[wib][m] = strt[dst] + pos;
    srcA[wib][m] = src;
  }

  const float* __restrict__ rp = &ef[(size_t)(tile * 16 + m) * 32 + g * 8];
  float4 f0 = *(const float4*)rp;
  float4 f1 = *(const float4*)(rp + 4);
  bf16x8 a;
  a[0] = (short)bfr(f0.x); a[1] = (short)bfr(f0.y);
  a[2] = (short)bfr(f0.z); a[3] = (short)bfr(f0.w);
  a[4] = (short)bfr(f1.x); a[5] = (short)bfr(f1.y);
  a[6] = (short)bfr(f1.z); a[7] = (short)bfr(f1.w);

  const bf16x8* __restrict__ bfp = (const bf16x8*)Bfrag;
  bf16x8 b0 = bfp[0 * 64 + lane];
  bf16x8 b1 = bfp[1 * 64 + lane];
  bf16x8 b2 = bfp[2 * 64 + lane];
  bf16x8 b3 = bfp[3 * 64 + lane];
  float cl0 = c[0 * 16 + m], cl1 = c[1 * 16 + m];
  float cl2 = c[2 * 16 + m], cl3 = c[3 * 16 + m];

  f32x4 z = {0.f, 0.f, 0.f, 0.f};
  f32x4 q0 = __builtin_amdgcn_mfma_f32_16x16x32_bf16(a, b0, z, 0, 0, 0);
  f32x4 q1 = __builtin_amdgcn_mfma_f32_16x16x32_bf16(a, b1, z, 0, 0, 0);
  f32x4 q2 = __builtin_amdgcn_mfma_f32_16x16x32_bf16(a, b2, z, 0, 0, 0);
  f32x4 q3 = __builtin_amdgcn_mfma_f32_16x16x32_bf16(a, b3, z, 0, 0, 0);

  unsigned short* __restrict__ lq = &ldsQ[wib][0];
#pragma unroll
  for (int r = 0; r < 4; ++r) {
    int mp = g * 4 + r;
    lq[mp * 72 + 0 * 16 + m] = (unsigned short)bfr(q0[r] + cl0);
    lq[mp * 72 + 1 * 16 + m] = (unsigned short)bfr(q1[r] + cl1);
    lq[mp * 72 + 2 * 16 + m] = (unsigned short)bfr(q2[r] + cl2);
    lq[mp * 72 + 3 * 16 + m] = (unsigned short)bfr(q3[r] + cl3);
  }
  __syncthreads();

  int m2 = lane >> 2, lo = lane & 3;
  uint4 w0 = *(const uint4*)&ldsQ[wib][m2 * 72 + lo * 16];
  uint4 w1 = *(const uint4*)&ldsQ[wib][m2 * 72 + lo * 16 + 8];
  int slot = slotA[wib][m2];
  int src = srcA[wib][m2];
  uint4 p0 = PRAh[(size_t)src * 8 + lo * 2];
  uint4 p1 = PRAh[(size_t)src * 8 + lo * 2 + 1];
  uint4 h0 = addrelu4(w0, p0);
  uint4 h1 = addrelu4(w1, p1);
  uint4* __restrict__ qp = (uint4*)(hS + (size_t)slot * 64);
  qp[lo * 2] = h0;
  qp[lo * 2 + 1] = h1;
}

// ---------------------------------------------------------------------------
// k_sum: streaming segment-sum of contiguous dst-sorted h rows.
// ---------------------------------------------------------------------------
__global__ __launch_bounds__(256) void k_sum(
    const unsigned short* __restrict__ hS, const int* __restrict__ strt,
    float* __restrict__ H) {
  int wib = threadIdx.x >> 6;
  int lane = threadIdx.x & 63;
  int n = blockIdx.x * 4 + wib;
  if (n >= NN) return;
  int s0 = strt[n], s1 = strt[n + 1];
  float acc = 0.f;
  int s = s0;
  for (; s + 4 <= s1; s += 4) {
    unsigned short a0 = hS[(size_t)(s + 0) * 64 + lane];
    unsigned short a1 = hS[(size_t)(s + 1) * 64 + lane];
    unsigned short a2 = hS[(size_t)(s + 2) * 64 + lane];
    unsigned short a3 = hS[(size_t)(s + 3) * 64 + lane];
    acc += (bf2f(a0) + bf2f(a1)) + (bf2f(a2) + bf2f(a3));
  }
  for (; s < s1; ++s) acc += bf2f(hS[(size_t)s * 64 + lane]);
  H[(size_t)n * 64 + lane] = acc;
}

// ---------------------------------------------------------------------------
// k_update4: 2 threads per node; each owns 32 output cols (first-layer h
// recomputed per half). pre = PRU + H@W2U + deg*d2 + bu1; out = relu(pre)@wu2.
// ---------------------------------------------------------------------------
__global__ __launch_bounds__(256) void k_update4(
    const float* __restrict__ H, const int* __restrict__ strt,
    const float* __restrict__ PRU,
    const float* __restrict__ W2U, const float* __restrict__ d2,
    const float* __restrict__ bu1,
    const float* __restrict__ wu2, const float* __restrict__ bu2,
    float* __restrict__ out) {
  int gid = blockIdx.x * 256 + threadIdx.x;
  int n = gid >> 1;
  int half = gid & 1;
  if (n >= NN) return;

  float Hr[64];
#pragma unroll
  for (int k = 0; k < 64; k += 4)
    *(float4*)&Hr[k] = *(const float4*)&H[(size_t)n * 64 + k];
  float deg = (float)(strt[n + 1] - strt[n]);

  float acc[32];
#pragma unroll
  for (int o = 0; o < 32; ++o) acc[o] = bu2[half * 32 + o];

  const float* __restrict__ prs = &PRU[(size_t)n * 64];
#pragma unroll 1
  for (int jc = 0; jc < 64; jc += 16) {
    float q[16];
#pragma unroll
    for (int jj = 0; jj < 16; ++jj) q[jj] = bu1[jc + jj] + deg * d2[jc + jj];
#pragma unroll
    for (int k = 0; k < 64; ++k) {
      float hv = Hr[k];
#pragma unroll
      for (int jj = 0; jj < 16; ++jj) q[jj] += hv * W2U[k * 64 + jc + jj];
    }
#pragma unroll
    for (int jj = 0; jj < 16; ++jj) {
      float h = fmaxf(prs[jc + jj] + q[jj], 0.f);
#pragma unroll
      for (int o = 0; o < 32; ++o)
        acc[o] += h * wu2[(jc + jj) * 64 + half * 32 + o];
    }
  }

#pragma unroll
  for (int o = 0; o < 32; o += 4)
    *(float4*)&out[(size_t)n * 64 + half * 32 + o] =
        make_float4(acc[o], acc[o + 1], acc[o + 2], acc[o + 3]);
}

// ---------------------------------------------------------------------------
// Fallback (ws too small): round-1 atomic scatter path
// ---------------------------------------------------------------------------
__global__ __launch_bounds__(256) void k_edge_at(
    const int* __restrict__ idx, const float* __restrict__ ef,
    const float* __restrict__ B, const float* __restrict__ c,
    const float* __restrict__ wm2, const float* __restrict__ bm2,
    const float* __restrict__ PRA, float* __restrict__ agg) {
  int e = blockIdx.x * 256 + threadIdx.x;
  if (e >= NE) return;
  int src = idx[e];
  int dst = idx[NE + e];
  float efr[32];
#pragma unroll
  for (int k = 0; k < 32; k += 4)
    *(float4*)&efr[k] = *(const float4*)&ef[(size_t)e * 32 + k];
  float m[64];
#pragma unroll
  for (int o = 0; o < 64; ++o) m[o] = bm2[o];
  const float* __restrict__ prs = &PRA[(size_t)src * 64];
#pragma unroll 1
  for (int jc = 0; jc < 64; jc += 16) {
    float q[16];
#pragma unroll
    for (int jj = 0; jj < 16; ++jj) q[jj] = c[jc + jj];
#pragma unroll
    for (int k = 0; k < 32; ++k) {
      float ev = efr[k];
#pragma unroll
      for (int jj = 0; jj < 16; ++jj) q[jj] += ev * B[k * 64 + jc + jj];
    }
#pragma unroll
    for (int jj = 0; jj < 16; ++jj) {
      float h = fmaxf(prs[jc + jj] + q[jj], 0.f);
#pragma unroll
      for (int o = 0; o < 64; ++o) m[o] += h * wm2[(jc + jj) * 64 + o];
    }
  }
  float* __restrict__ ap = &agg[(size_t)dst * 64];
#pragma unroll
  for (int o = 0; o < 64; ++o) atomicAdd(&ap[o], m[o]);
}

__global__ __launch_bounds__(256) void k_update_at(
    const float* __restrict__ agg, const float* __restrict__ PRU,
    const float* __restrict__ wu1, const float* __restrict__ bu1,
    const float* __restrict__ wu2, const float* __restrict__ bu2,
    float* __restrict__ out) {
  int n = blockIdx.x * 256 + threadIdx.x;
  if (n >= NN) return;
  float ar[64];
#pragma unroll
  for (int k = 0; k < 64; k += 4)
    *(float4*)&ar[k] = *(const float4*)&agg[(size_t)n * 64 + k];
  float acc[64];
#pragma unroll
  for (int o = 0; o < 64; ++o) acc[o] = bu2[o];
  const float* __restrict__ prs = &PRU[(size_t)n * 64];
#pragma unroll 1
  for (int jc = 0; jc < 64; jc += 16) {
    float q[16];
#pragma unroll
    for (int jj = 0; jj < 16; ++jj) q[jj] = bu1[jc + jj];
#pragma unroll
    for (int k = 0; k < 64; ++k) {
      float av = ar[k];
#pragma unroll
      for (int jj = 0; jj < 16; ++jj) q[jj] += av * wu1[(128 + k) * 64 + jc + jj];
    }
#pragma unroll
    for (int jj = 0; jj < 16; ++jj) {
      float h = fmaxf(prs[jc + jj] + q[jj], 0.f);
#pragma unroll
      for (int o = 0; o < 64; ++o) acc[o] += h * wu2[(jc + jj) * 64 + o];
    }
  }
#pragma unroll
  for (int o = 0; o < 64; o += 4)
    *(float4*)&out[(size_t)n * 64 + o] = make_float4(acc[o], acc[o + 1], acc[o + 2], acc[o + 3]);
}

extern "C" void kernel_launch(void* const* d_in, const int* in_sizes, int n_in,
                              void* d_out, int out_size, void* d_ws, size_t ws_size,
                              hipStream_t stream) {
  const float* nf  = (const float*)d_in[0];
  const int*   idx = (const int*)d_in[1];
  const float* ef  = (const float*)d_in[2];
  const float* wn  = (const float*)d_in[3];
  const float* bn  = (const float*)d_in[4];
  const float* we  = (const float*)d_in[5];
  const float* be  = (const float*)d_in[6];
  const float* wm1 = (const float*)d_in[7];
  const float* bm1 = (const float*)d_in[8];
  const float* wm2 = (const float*)d_in[9];
  const float* bm2 = (const float*)d_in[10];
  const float* wu1 = (const float*)d_in[11];
  const float* bu1 = (const float*)d_in[12];
  const float* wu2 = (const float*)d_in[13];
  const float* bu2 = (const float*)d_in[14];
  float* out = (float*)d_out;

  float* ws   = (float*)d_ws;
  float* M    = ws + OFF_M;
  float* B    = ws + OFF_B;
  float* c    = ws + OFF_C;
  float* W2U  = ws + OFF_W2U;
  float* d2   = ws + OFF_D2;
  uint4* Bfrg = (uint4*)(ws + OFF_BFRG);
  uint4* Mfrg = (uint4*)(ws + OFF_MFRG);
  int*   bsum = (int*)(ws + OFF_BSUM);
  int*   boff = (int*)(ws + OFF_BOFF);
  float* PRA  = ws + OFF_PRA;
  unsigned* PRAh = (unsigned*)(ws + OFF_PRAH);
  float* PRU  = ws + OFF_PRU;
  float* H    = ws + OFF_H;
  int*   hist = (int*)(ws + OFF_HIST);
  int*   cur  = (int*)(ws + OFF_CUR);
  int*   strt = (int*)(ws + OFF_STRT);
  unsigned short* hS = (unsigned short*)(ws + OFF_HS);

  const int SCAN_BLOCKS = (NN + 1023) / 1024;  // 98
  const int FOLD_THREADS = 16384 + 2048 + 64 + 4096 + 64 + 256 + 2048;
  const int NTILE = NN / 16;  // 6250

  k_fold<<<(FOLD_THREADS + 255) / 256, 256, 0, stream>>>(
      wn, bn, we, be, wm1, bm1, wm2, bm2, wu1, M, B, c, W2U, d2, Bfrg, Mfrg);
  k_node2<<<(NTILE + 3) / 4, 256, 0, stream>>>(nf, Mfrg, PRA, PRU);
  k_prah<<<(NN * 32 + 255) / 256, 256, 0, stream>>>((const float2*)PRA, PRAh);

  if (ws_size >= (size_t)WS_UNITS * 4) {
    hipMemsetAsync(hist, 0, (size_t)2 * NN * sizeof(int), stream);
    k_hist<<<(NE + 255) / 256, 256, 0, stream>>>(idx, hist);
    k_scanA<<<SCAN_BLOCKS, 1024, 0, stream>>>(hist, strt, bsum);
    k_scanB<<<1, 128, 0, stream>>>(bsum, boff, strt, SCAN_BLOCKS);
    k_scanC<<<SCAN_BLOCKS, 1024, 0, stream>>>(strt, boff);
    k_msgh<<<NE / 16 / 4, 256, 0, stream>>>(idx, strt, cur, ef, Bfrg, c,
                                            (const uint4*)PRAh, hS);
    k_sum<<<(NN + 3) / 4, 256, 0, stream>>>(hS, strt, H);
    k_update4<<<(2 * NN + 255) / 256, 256, 0, stream>>>(
        H, strt, PRU, W2U, d2, bu1, wu2, bu2, out);
  } else {
    hipMemsetAsync(H, 0, (size_t)NN * 64 * sizeof(float), stream);
    k_edge_at<<<(NE + 255) / 256, 256, 0, stream>>>(idx, ef, B, c, wm2, bm2, PRA, H);
    k_update_at<<<(NN + 255) / 256, 256, 0, stream>>>(
        H, PRU, wu1, bu1, wu2, bu2, out);
  }
}

// Round 16
// 369.990 us; speedup vs baseline: 1.7740x; 1.6230x over previous
//
#include <hip/hip_runtime.h>

#define NN 100000
#define NE 1600000

typedef __attribute__((ext_vector_type(8))) short bf16x8;
typedef __attribute__((ext_vector_type(4))) float f32x4;

// ---------------------------------------------------------------------------
// Workspace layout in 4-byte units (~296 MB; round-5 tier-1 proved >=494 MB)
// ---------------------------------------------------------------------------
#define OFF_M    0                         // 128*128 folded [A | wu1_top] (fallback)
#define OFF_B    (OFF_M + 16384)           // 32*64   we @ wm1_bot (fp32, fallback)
#define OFF_C    (OFF_B + 2048)            // 64      folded msg bias
#define OFF_W2U  (OFF_C + 64)              // 64*64   wm2 @ wu1_bot (f32, unused fast path)
#define OFF_D2   (OFF_W2U + 4096)          // 64      bm2 @ wu1_bot
#define OFF_BFRG (OFF_D2 + 64)             // 4*64 uint4 = 1024 dwords
#define OFF_MFRG (OFF_BFRG + 1024)         // 32*64 uint4 = 8192 dwords
#define OFF_W2UF (OFF_MFRG + 8192)         // 8*64 uint4 = 2048 dwords
#define OFF_WU2F (OFF_W2UF + 2048)         // 8*64 uint4 = 2048 dwords
#define OFF_BSUM (OFF_WU2F + 2048)         // 128 block sums (scan)
#define OFF_BOFF (OFF_BSUM + 128)          // 128 block offsets (scan)
#define OFF_PRA  (OFF_BOFF + 128)          // NN*64 f32
#define OFF_PRAH (OFF_PRA + NN * 64)       // NN*32: PRA in bf16
#define OFF_PRU  (OFF_PRAH + NN * 32)      // NN*64
#define OFF_H    (OFF_PRU + NN * 64)       // NN*64  (agg in fallback)
#define OFF_HIST (OFF_H + NN * 64)         // NN
#define OFF_CUR  (OFF_HIST + NN)           // NN
#define OFF_STRT (OFF_CUR + NN)            // NN+1 (+pad)
#define OFF_HS   (OFF_STRT + NN + 4)       // NE*64 bf16 = NE*32 dwords
#define WS_UNITS (OFF_HS + NE * 32)

__device__ __forceinline__ unsigned bfr(float x) {
  unsigned u = __float_as_uint(x);
  return (u + 0x7fffu + ((u >> 16) & 1u)) >> 16;
}
__device__ __forceinline__ float bf2f(unsigned short h) {
  return __uint_as_float(((unsigned)h) << 16);
}
__device__ __forceinline__ unsigned addrelu1(unsigned qa, unsigned pb) {
  float lo = __uint_as_float((qa & 0xffffu) << 16) +
             __uint_as_float((pb & 0xffffu) << 16);
  float hi = __uint_as_float(qa & 0xffff0000u) +
             __uint_as_float(pb & 0xffff0000u);
  lo = fmaxf(lo, 0.f);
  hi = fmaxf(hi, 0.f);
  return bfr(lo) | (bfr(hi) << 16);
}
__device__ __forceinline__ uint4 addrelu4(uint4 q, uint4 p) {
  return make_uint4(addrelu1(q.x, p.x), addrelu1(q.y, p.y),
                    addrelu1(q.z, p.z), addrelu1(q.w, p.w));
}

// ---------------------------------------------------------------------------
// Weight folding + bf16 fragment packs.
//   M / B / c / W2U / d2 as before.
//   Bfrag : msg-MFMA B frags.  Mfrag : node-MFMA frags (K=128).
//   W2Uf  : update layer-1 frags (W2U = wm2@wu1_bot, K=64, recomputed).
//   wu2f  : update layer-2 frags (wu2, K=64).
// ---------------------------------------------------------------------------
__global__ __launch_bounds__(256) void k_fold(
    const float* __restrict__ wn, const float* __restrict__ bn,
    const float* __restrict__ we, const float* __restrict__ be,
    const float* __restrict__ wm1, const float* __restrict__ bm1,
    const float* __restrict__ wm2, const float* __restrict__ bm2,
    const float* __restrict__ wu1, const float* __restrict__ wu2,
    float* __restrict__ M, float* __restrict__ B, float* __restrict__ c,
    float* __restrict__ W2U, float* __restrict__ d2,
    uint4* __restrict__ Bfrag, uint4* __restrict__ Mfrag,
    uint4* __restrict__ W2Uf, uint4* __restrict__ wu2f) {
  int t = blockIdx.x * 256 + threadIdx.x;
  if (t < 16384) {
    int k = t >> 7, j = t & 127;
    float acc;
    if (j < 64) {
      acc = 0.f;
      for (int h = 0; h < 64; ++h) acc += wn[k * 64 + h] * wm1[h * 64 + j];
    } else {
      acc = wu1[k * 64 + (j - 64)];
    }
    M[t] = acc;
  } else if (t < 16384 + 2048) {
    int u = t - 16384;
    int k = u >> 6, j = u & 63;
    float acc = 0.f;
    for (int h = 0; h < 64; ++h) acc += we[k * 64 + h] * wm1[(64 + h) * 64 + j];
    B[u] = acc;
  } else if (t < 16384 + 2048 + 64) {
    int j = t - (16384 + 2048);
    float acc = bm1[j];
    for (int h = 0; h < 64; ++h)
      acc += bn[h] * wm1[h * 64 + j] + be[h] * wm1[(64 + h) * 64 + j];
    c[j] = acc;
  } else if (t < 16384 + 2048 + 64 + 4096) {
    int u = t - (16384 + 2048 + 64);
    int k = u >> 6, j = u & 63;
    float acc = 0.f;
    for (int h = 0; h < 64; ++h) acc += wm2[k * 64 + h] * wu1[(128 + h) * 64 + j];
    W2U[u] = acc;
  } else if (t < 16384 + 2048 + 64 + 4096 + 64) {
    int j = t - (16384 + 2048 + 64 + 4096);
    float acc = 0.f;
    for (int h = 0; h < 64; ++h) acc += bm2[h] * wu1[(128 + h) * 64 + j];
    d2[j] = acc;
  } else if (t < 16384 + 2048 + 64 + 4096 + 64 + 256) {
    int u = t - (16384 + 2048 + 64 + 4096 + 64);
    int jb = u >> 6, l = u & 63;
    int g = l >> 4, n = l & 15;
    unsigned s[8];
#pragma unroll
    for (int i = 0; i < 8; ++i) {
      int k = g * 8 + i;
      int j = jb * 16 + n;
      float acc = 0.f;
      for (int h = 0; h < 64; ++h)
        acc += we[k * 64 + h] * wm1[(64 + h) * 64 + j];
      s[i] = bfr(acc);
    }
    Bfrag[jb * 64 + l] = make_uint4(s[0] | (s[1] << 16), s[2] | (s[3] << 16),
                                    s[4] | (s[5] << 16), s[6] | (s[7] << 16));
  } else if (t < 16384 + 2048 + 64 + 4096 + 64 + 256 + 2048) {
    int u = t - (16384 + 2048 + 64 + 4096 + 64 + 256);
    int jb = u >> 8, kb = (u >> 6) & 3, l = u & 63;
    int g = l >> 4, n = l & 15;
    int j = jb * 16 + n;
    unsigned s[8];
#pragma unroll
    for (int i = 0; i < 8; ++i) {
      int k = kb * 32 + g * 8 + i;
      float acc;
      if (j < 64) {
        acc = 0.f;
        for (int h = 0; h < 64; ++h) acc += wn[k * 64 + h] * wm1[h * 64 + j];
      } else {
        acc = wu1[k * 64 + (j - 64)];
      }
      s[i] = bfr(acc);
    }
    Mfrag[(jb * 4 + kb) * 64 + l] =
        make_uint4(s[0] | (s[1] << 16), s[2] | (s[3] << 16),
                   s[4] | (s[5] << 16), s[6] | (s[7] << 16));
  } else if (t < 16384 + 2048 + 64 + 4096 + 64 + 256 + 2048 + 512) {
    int u = t - (16384 + 2048 + 64 + 4096 + 64 + 256 + 2048);
    int jk = u >> 6, l = u & 63;   // jk = jb*2+kb
    int jb = jk >> 1, kb = jk & 1;
    int g = l >> 4, n = l & 15;
    int j = jb * 16 + n;
    unsigned s[8];
#pragma unroll
    for (int i = 0; i < 8; ++i) {
      int k = kb * 32 + g * 8 + i;
      float acc = 0.f;
      for (int h = 0; h < 64; ++h)
        acc += wm2[k * 64 + h] * wu1[(128 + h) * 64 + j];
      s[i] = bfr(acc);
    }
    W2Uf[jk * 64 + l] = make_uint4(s[0] | (s[1] << 16), s[2] | (s[3] << 16),
                                   s[4] | (s[5] << 16), s[6] | (s[7] << 16));
  } else if (t < 16384 + 2048 + 64 + 4096 + 64 + 256 + 2048 + 512 + 512) {
    int u = t - (16384 + 2048 + 64 + 4096 + 64 + 256 + 2048 + 512);
    int jk = u >> 6, l = u & 63;
    int jb = jk >> 1, kb = jk & 1;
    int g = l >> 4, n = l & 15;
    unsigned s[8];
#pragma unroll
    for (int i = 0; i < 8; ++i)
      s[i] = bfr(wu2[(size_t)(kb * 32 + g * 8 + i) * 64 + jb * 16 + n]);
    wu2f[jk * 64 + l] = make_uint4(s[0] | (s[1] << 16), s[2] | (s[3] << 16),
                                   s[4] | (s[5] << 16), s[6] | (s[7] << 16));
  }
}

// ---------------------------------------------------------------------------
// k_node2: MFMA node precompute (proven round 15). Wave per 16-node tile.
// ---------------------------------------------------------------------------
__global__ __launch_bounds__(256) void k_node2(
    const float* __restrict__ nf, const uint4* __restrict__ Mfrag,
    float* __restrict__ PRA, float* __restrict__ PRU) {
  int wib = threadIdx.x >> 6;
  int lane = threadIdx.x & 63;
  int tile = blockIdx.x * 4 + wib;
  if (tile >= NN / 16) return;
  int m = lane & 15, g = lane >> 4;
  int node = tile * 16 + m;

  bf16x8 a[4];
#pragma unroll
  for (int kb = 0; kb < 4; ++kb) {
    const float* __restrict__ rp = &nf[(size_t)node * 128 + kb * 32 + g * 8];
    float4 f0 = *(const float4*)rp;
    float4 f1 = *(const float4*)(rp + 4);
    bf16x8 v;
    v[0] = (short)bfr(f0.x); v[1] = (short)bfr(f0.y);
    v[2] = (short)bfr(f0.z); v[3] = (short)bfr(f0.w);
    v[4] = (short)bfr(f1.x); v[5] = (short)bfr(f1.y);
    v[6] = (short)bfr(f1.z); v[7] = (short)bfr(f1.w);
    a[kb] = v;
  }

  const bf16x8* __restrict__ mfp = (const bf16x8*)Mfrag;
#pragma unroll
  for (int jb = 0; jb < 8; ++jb) {
    f32x4 acc = {0.f, 0.f, 0.f, 0.f};
    acc = __builtin_amdgcn_mfma_f32_16x16x32_bf16(a[0], mfp[(jb * 4 + 0) * 64 + lane], acc, 0, 0, 0);
    acc = __builtin_amdgcn_mfma_f32_16x16x32_bf16(a[1], mfp[(jb * 4 + 1) * 64 + lane], acc, 0, 0, 0);
    acc = __builtin_amdgcn_mfma_f32_16x16x32_bf16(a[2], mfp[(jb * 4 + 2) * 64 + lane], acc, 0, 0, 0);
    acc = __builtin_amdgcn_mfma_f32_16x16x32_bf16(a[3], mfp[(jb * 4 + 3) * 64 + lane], acc, 0, 0, 0);
    float* __restrict__ dst = (jb < 4) ? PRA : PRU;
    int col = (jb & 3) * 16 + m;
#pragma unroll
    for (int r = 0; r < 4; ++r) {
      int row = tile * 16 + g * 4 + r;
      dst[(size_t)row * 64 + col] = acc[r];
    }
  }
}

// PRAh pack: coalesced f32 pairs -> bf16x2
__global__ __launch_bounds__(256) void k_prah(
    const float2* __restrict__ PRA2, unsigned* __restrict__ PRAh) {
  int t = blockIdx.x * 256 + threadIdx.x;
  if (t < NN * 32) {
    float2 v = PRA2[t];
    PRAh[t] = bfr(v.x) | (bfr(v.y) << 16);
  }
}

// ---------------------------------------------------------------------------
// Counting sort: hist -> 3-phase scan
// ---------------------------------------------------------------------------
__global__ __launch_bounds__(256) void k_hist(const int* __restrict__ idx,
                                              int* __restrict__ hist) {
  int e = blockIdx.x * 256 + threadIdx.x;
  if (e < NE) atomicAdd(&hist[idx[NE + e]], 1);
}

__global__ __launch_bounds__(1024) void k_scanA(const int* __restrict__ hist,
                                                int* __restrict__ strt,
                                                int* __restrict__ bsum) {
  __shared__ int lds[1024];
  int t = threadIdx.x;
  int i = blockIdx.x * 1024 + t;
  int v = (i < NN) ? hist[i] : 0;
  lds[t] = v;
  __syncthreads();
  for (int off = 1; off < 1024; off <<= 1) {
    int u = (t >= off) ? lds[t - off] : 0;
    __syncthreads();
    lds[t] += u;
    __syncthreads();
  }
  if (i < NN) strt[i] = lds[t] - v;
  if (t == 1023) bsum[blockIdx.x] = lds[1023];
}

__global__ __launch_bounds__(128) void k_scanB(const int* __restrict__ bsum,
                                               int* __restrict__ boff,
                                               int* __restrict__ strt,
                                               int nblocks) {
  __shared__ int lds[128];
  int t = threadIdx.x;
  int v = (t < nblocks) ? bsum[t] : 0;
  lds[t] = v;
  __syncthreads();
  for (int off = 1; off < 128; off <<= 1) {
    int u = (t >= off) ? lds[t - off] : 0;
    __syncthreads();
    lds[t] += u;
    __syncthreads();
  }
  if (t < nblocks) boff[t] = lds[t] - v;
  if (t == 127) strt[NN] = lds[127];
}

__global__ __launch_bounds__(1024) void k_scanC(int* __restrict__ strt,
                                                const int* __restrict__ boff) {
  int i = blockIdx.x * 1024 + threadIdx.x;
  if (i < NN) strt[i] += boff[blockIdx.x];
}

// ---------------------------------------------------------------------------
// k_msgh: wave per 16-edge tile; MFMA q=ef@B + bias -> LDS transpose ->
// add PRAh[src] (bf16), relu, one 128B burst per edge to dst-sorted slot.
// ---------------------------------------------------------------------------
__global__ __launch_bounds__(256) void k_msgh(
    const int* __restrict__ idx, const int* __restrict__ strt,
    int* __restrict__ cursor, const float* __restrict__ ef,
    const uint4* __restrict__ Bfrag, const float* __restrict__ c,
    const uint4* __restrict__ PRAh, unsigned short* __restrict__ hS) {
  __shared__ unsigned short ldsQ[4][16 * 72];
  __shared__ int slotA[4][16];
  __shared__ int srcA[4][16];
  int wib = threadIdx.x >> 6;
  int lane = threadIdx.x & 63;
  int m = lane & 15, g = lane >> 4;
  int tile = blockIdx.x * 4 + wib;

  if (lane < 16) {
    int e = tile * 16 + m;
    int src = idx[e];
    int dst = idx[NE + e];
    int pos = atomicAdd(&cursor[dst], 1);
    slotA[wib][m] = strt[dst] + pos;
    srcA[wib][m] = src;
  }

  const float* __restrict__ rp = &ef[(size_t)(tile * 16 + m) * 32 + g * 8];
  float4 f0 = *(const float4*)rp;
  float4 f1 = *(const float4*)(rp + 4);
  bf16x8 a;
  a[0] = (short)bfr(f0.x); a[1] = (short)bfr(f0.y);
  a[2] = (short)bfr(f0.z); a[3] = (short)bfr(f0.w);
  a[4] = (short)bfr(f1.x); a[5] = (short)bfr(f1.y);
  a[6] = (short)bfr(f1.z); a[7] = (short)bfr(f1.w);

  const bf16x8* __restrict__ bfp = (const bf16x8*)Bfrag;
  bf16x8 b0 = bfp[0 * 64 + lane];
  bf16x8 b1 = bfp[1 * 64 + lane];
  bf16x8 b2 = bfp[2 * 64 + lane];
  bf16x8 b3 = bfp[3 * 64 + lane];
  float cl0 = c[0 * 16 + m], cl1 = c[1 * 16 + m];
  float cl2 = c[2 * 16 + m], cl3 = c[3 * 16 + m];

  f32x4 z = {0.f, 0.f, 0.f, 0.f};
  f32x4 q0 = __builtin_amdgcn_mfma_f32_16x16x32_bf16(a, b0, z, 0, 0, 0);
  f32x4 q1 = __builtin_amdgcn_mfma_f32_16x16x32_bf16(a, b1, z, 0, 0, 0);
  f32x4 q2 = __builtin_amdgcn_mfma_f32_16x16x32_bf16(a, b2, z, 0, 0, 0);
  f32x4 q3 = __builtin_amdgcn_mfma_f32_16x16x32_bf16(a, b3, z, 0, 0, 0);

  unsigned short* __restrict__ lq = &ldsQ[wib][0];
#pragma unroll
  for (int r = 0; r < 4; ++r) {
    int mp = g * 4 + r;
    lq[mp * 72 + 0 * 16 + m] = (unsigned short)bfr(q0[r] + cl0);
    lq[mp * 72 + 1 * 16 + m] = (unsigned short)bfr(q1[r] + cl1);
    lq[mp * 72 + 2 * 16 + m] = (unsigned short)bfr(q2[r] + cl2);
    lq[mp * 72 + 3 * 16 + m] = (unsigned short)bfr(q3[r] + cl3);
  }
  __syncthreads();

  int m2 = lane >> 2, lo = lane & 3;
  uint4 w0 = *(const uint4*)&ldsQ[wib][m2 * 72 + lo * 16];
  uint4 w1 = *(const uint4*)&ldsQ[wib][m2 * 72 + lo * 16 + 8];
  int slot = slotA[wib][m2];
  int src = srcA[wib][m2];
  uint4 p0 = PRAh[(size_t)src * 8 + lo * 2];
  uint4 p1 = PRAh[(size_t)src * 8 + lo * 2 + 1];
  uint4 h0 = addrelu4(w0, p0);
  uint4 h1 = addrelu4(w1, p1);
  uint4* __restrict__ qp = (uint4*)(hS + (size_t)slot * 64);
  qp[lo * 2] = h0;
  qp[lo * 2 + 1] = h1;
}

// ---------------------------------------------------------------------------
// k_sum: streaming segment-sum of contiguous dst-sorted h rows.
// ---------------------------------------------------------------------------
__global__ __launch_bounds__(256) void k_sum(
    const unsigned short* __restrict__ hS, const int* __restrict__ strt,
    float* __restrict__ H) {
  int wib = threadIdx.x >> 6;
  int lane = threadIdx.x & 63;
  int n = blockIdx.x * 4 + wib;
  if (n >= NN) return;
  int s0 = strt[n], s1 = strt[n + 1];
  float acc = 0.f;
  int s = s0;
  for (; s + 4 <= s1; s += 4) {
    unsigned short a0 = hS[(size_t)(s + 0) * 64 + lane];
    unsigned short a1 = hS[(size_t)(s + 1) * 64 + lane];
    unsigned short a2 = hS[(size_t)(s + 2) * 64 + lane];
    unsigned short a3 = hS[(size_t)(s + 3) * 64 + lane];
    acc += (bf2f(a0) + bf2f(a1)) + (bf2f(a2) + bf2f(a3));
  }
  for (; s < s1; ++s) acc += bf2f(hS[(size_t)s * 64 + lane]);
  H[(size_t)n * 64 + lane] = acc;
}

// ---------------------------------------------------------------------------
// k_update5: MFMA update MLP. Wave per 16-node tile (k_node2 recipe):
//   layer1: pre = H@W2U (2 MFMA per 16-col block) + PRU + deg*d2 + bu1,
//           relu -> bf16 -> per-wave LDS transpose (72-short stride)
//   layer2: out = h@wu2 (2 MFMA per block) + bu2
// ---------------------------------------------------------------------------
__global__ __launch_bounds__(256) void k_update5(
    const float* __restrict__ H, const int* __restrict__ strt,
    const float* __restrict__ PRU,
    const uint4* __restrict__ W2Uf, const float* __restrict__ d2,
    const float* __restrict__ bu1,
    const uint4* __restrict__ wu2f, const float* __restrict__ bu2,
    float* __restrict__ out) {
  __shared__ unsigned short ldsH[4][16 * 72];
  int wib = threadIdx.x >> 6;
  int lane = threadIdx.x & 63;
  int tile = blockIdx.x * 4 + wib;
  if (tile >= NN / 16) return;
  int m = lane & 15, g = lane >> 4;
  int node = tile * 16 + m;

  // A-frags from H (bf16), K=64
  bf16x8 ah[2];
#pragma unroll
  for (int kb = 0; kb < 2; ++kb) {
    const float* __restrict__ rp = &H[(size_t)node * 64 + kb * 32 + g * 8];
    float4 f0 = *(const float4*)rp;
    float4 f1 = *(const float4*)(rp + 4);
    bf16x8 v;
    v[0] = (short)bfr(f0.x); v[1] = (short)bfr(f0.y);
    v[2] = (short)bfr(f0.z); v[3] = (short)bfr(f0.w);
    v[4] = (short)bfr(f1.x); v[5] = (short)bfr(f1.y);
    v[6] = (short)bfr(f1.z); v[7] = (short)bfr(f1.w);
    ah[kb] = v;
  }

  const bf16x8* __restrict__ w2p = (const bf16x8*)W2Uf;
  const bf16x8* __restrict__ wup = (const bf16x8*)wu2f;
  unsigned short* __restrict__ lh = &ldsH[wib][0];

  // layer 1
#pragma unroll
  for (int jb = 0; jb < 4; ++jb) {
    f32x4 acc = {0.f, 0.f, 0.f, 0.f};
    acc = __builtin_amdgcn_mfma_f32_16x16x32_bf16(ah[0], w2p[(jb * 2 + 0) * 64 + lane], acc, 0, 0, 0);
    acc = __builtin_amdgcn_mfma_f32_16x16x32_bf16(ah[1], w2p[(jb * 2 + 1) * 64 + lane], acc, 0, 0, 0);
    int col = jb * 16 + m;
    float dc = d2[col], bc = bu1[col];
#pragma unroll
    for (int r = 0; r < 4; ++r) {
      int row = tile * 16 + g * 4 + r;
      float deg = (float)(strt[row + 1] - strt[row]);
      float pre = acc[r] + PRU[(size_t)row * 64 + col] + deg * dc + bc;
      lh[(g * 4 + r) * 72 + col] = (unsigned short)bfr(fmaxf(pre, 0.f));
    }
  }
  __syncthreads();

  // layer 2: A-frags from LDS (row m, k = kb*32+g*8..+7)
  bf16x8 a2[2];
  a2[0] = *(const bf16x8*)&lh[m * 72 + 0 * 32 + g * 8];
  a2[1] = *(const bf16x8*)&lh[m * 72 + 1 * 32 + g * 8];
#pragma unroll
  for (int jb = 0; jb < 4; ++jb) {
    f32x4 acc = {0.f, 0.f, 0.f, 0.f};
    acc = __builtin_amdgcn_mfma_f32_16x16x32_bf16(a2[0], wup[(jb * 2 + 0) * 64 + lane], acc, 0, 0, 0);
    acc = __builtin_amdgcn_mfma_f32_16x16x32_bf16(a2[1], wup[(jb * 2 + 1) * 64 + lane], acc, 0, 0, 0);
    int col = jb * 16 + m;
    float bc = bu2[col];
#pragma unroll
    for (int r = 0; r < 4; ++r) {
      int row = tile * 16 + g * 4 + r;
      out[(size_t)row * 64 + col] = acc[r] + bc;
    }
  }
}

// ---------------------------------------------------------------------------
// Fallback (ws too small): round-1 atomic scatter path
// ---------------------------------------------------------------------------
__global__ __launch_bounds__(256) void k_edge_at(
    const int* __restrict__ idx, const float* __restrict__ ef,
    const float* __restrict__ B, const float* __restrict__ c,
    const float* __restrict__ wm2, const float* __restrict__ bm2,
    const float* __restrict__ PRA, float* __restrict__ agg) {
  int e = blockIdx.x * 256 + threadIdx.x;
  if (e >= NE) return;
  int src = idx[e];
  int dst = idx[NE + e];
  float efr[32];
#pragma unroll
  for (int k = 0; k < 32; k += 4)
    *(float4*)&efr[k] = *(const float4*)&ef[(size_t)e * 32 + k];
  float m[64];
#pragma unroll
  for (int o = 0; o < 64; ++o) m[o] = bm2[o];
  const float* __restrict__ prs = &PRA[(size_t)src * 64];
#pragma unroll 1
  for (int jc = 0; jc < 64; jc += 16) {
    float q[16];
#pragma unroll
    for (int jj = 0; jj < 16; ++jj) q[jj] = c[jc + jj];
#pragma unroll
    for (int k = 0; k < 32; ++k) {
      float ev = efr[k];
#pragma unroll
      for (int jj = 0; jj < 16; ++jj) q[jj] += ev * B[k * 64 + jc + jj];
    }
#pragma unroll
    for (int jj = 0; jj < 16; ++jj) {
      float h = fmaxf(prs[jc + jj] + q[jj], 0.f);
#pragma unroll
      for (int o = 0; o < 64; ++o) m[o] += h * wm2[(jc + jj) * 64 + o];
    }
  }
  float* __restrict__ ap = &agg[(size_t)dst * 64];
#pragma unroll
  for (int o = 0; o < 64; ++o) atomicAdd(&ap[o], m[o]);
}

__global__ __launch_bounds__(256) void k_update_at(
    const float* __restrict__ agg, const float* __restrict__ PRU,
    const float* __restrict__ wu1, const float* __restrict__ bu1,
    const float* __restrict__ wu2, const float* __restrict__ bu2,
    float* __restrict__ out) {
  int n = blockIdx.x * 256 + threadIdx.x;
  if (n >= NN) return;
  float ar[64];
#pragma unroll
  for (int k = 0; k < 64; k += 4)
    *(float4*)&ar[k] = *(const float4*)&agg[(size_t)n * 64 + k];
  float acc[64];
#pragma unroll
  for (int o = 0; o < 64; ++o) acc[o] = bu2[o];
  const float* __restrict__ prs = &PRU[(size_t)n * 64];
#pragma unroll 1
  for (int jc = 0; jc < 64; jc += 16) {
    float q[16];
#pragma unroll
    for (int jj = 0; jj < 16; ++jj) q[jj] = bu1[jc + jj];
#pragma unroll
    for (int k = 0; k < 64; ++k) {
      float av = ar[k];
#pragma unroll
      for (int jj = 0; jj < 16; ++jj) q[jj] += av * wu1[(128 + k) * 64 + jc + jj];
    }
#pragma unroll
    for (int jj = 0; jj < 16; ++jj) {
      float h = fmaxf(prs[jc + jj] + q[jj], 0.f);
#pragma unroll
      for (int o = 0; o < 64; ++o) acc[o] += h * wu2[(jc + jj) * 64 + o];
    }
  }
#pragma unroll
  for (int o = 0; o < 64; o += 4)
    *(float4*)&out[(size_t)n * 64 + o] = make_float4(acc[o], acc[o + 1], acc[o + 2], acc[o + 3]);
}

extern "C" void kernel_launch(void* const* d_in, const int* in_sizes, int n_in,
                              void* d_out, int out_size, void* d_ws, size_t ws_size,
                              hipStream_t stream) {
  const float* nf  = (const float*)d_in[0];
  const int*   idx = (const int*)d_in[1];
  const float* ef  = (const float*)d_in[2];
  const float* wn  = (const float*)d_in[3];
  const float* bn  = (const float*)d_in[4];
  const float* we  = (const float*)d_in[5];
  const float* be  = (const float*)d_in[6];
  const float* wm1 = (const float*)d_in[7];
  const float* bm1 = (const float*)d_in[8];
  const float* wm2 = (const float*)d_in[9];
  const float* bm2 = (const float*)d_in[10];
  const float* wu1 = (const float*)d_in[11];
  const float* bu1 = (const float*)d_in[12];
  const float* wu2 = (const float*)d_in[13];
  const float* bu2 = (const float*)d_in[14];
  float* out = (float*)d_out;

  float* ws   = (float*)d_ws;
  float* M    = ws + OFF_M;
  float* B    = ws + OFF_B;
  float* c    = ws + OFF_C;
  float* W2U  = ws + OFF_W2U;
  float* d2   = ws + OFF_D2;
  uint4* Bfrg = (uint4*)(ws + OFF_BFRG);
  uint4* Mfrg = (uint4*)(ws + OFF_MFRG);
  uint4* W2Uf = (uint4*)(ws + OFF_W2UF);
  uint4* wu2f = (uint4*)(ws + OFF_WU2F);
  int*   bsum = (int*)(ws + OFF_BSUM);
  int*   boff = (int*)(ws + OFF_BOFF);
  float* PRA  = ws + OFF_PRA;
  unsigned* PRAh = (unsigned*)(ws + OFF_PRAH);
  float* PRU  = ws + OFF_PRU;
  float* H    = ws + OFF_H;
  int*   hist = (int*)(ws + OFF_HIST);
  int*   cur  = (int*)(ws + OFF_CUR);
  int*   strt = (int*)(ws + OFF_STRT);
  unsigned short* hS = (unsigned short*)(ws + OFF_HS);

  const int SCAN_BLOCKS = (NN + 1023) / 1024;  // 98
  const int FOLD_THREADS = 16384 + 2048 + 64 + 4096 + 64 + 256 + 2048 + 512 + 512;
  const int NTILE = NN / 16;  // 6250

  k_fold<<<(FOLD_THREADS + 255) / 256, 256, 0, stream>>>(
      wn, bn, we, be, wm1, bm1, wm2, bm2, wu1, wu2,
      M, B, c, W2U, d2, Bfrg, Mfrg, W2Uf, wu2f);
  k_node2<<<(NTILE + 3) / 4, 256, 0, stream>>>(nf, Mfrg, PRA, PRU);
  k_prah<<<(NN * 32 + 255) / 256, 256, 0, stream>>>((const float2*)PRA, PRAh);

  if (ws_size >= (size_t)WS_UNITS * 4) {
    hipMemsetAsync(hist, 0, (size_t)2 * NN * sizeof(int), stream);
    k_hist<<<(NE + 255) / 256, 256, 0, stream>>>(idx, hist);
    k_scanA<<<SCAN_BLOCKS, 1024, 0, stream>>>(hist, strt, bsum);
    k_scanB<<<1, 128, 0, stream>>>(bsum, boff, strt, SCAN_BLOCKS);
    k_scanC<<<SCAN_BLOCKS, 1024, 0, stream>>>(strt, boff);
    k_msgh<<<NE / 16 / 4, 256, 0, stream>>>(idx, strt, cur, ef, Bfrg, c,
                                            (const uint4*)PRAh, hS);
    k_sum<<<(NN + 3) / 4, 256, 0, stream>>>(hS, strt, H);
    k_update5<<<(NTILE + 3) / 4, 256, 0, stream>>>(
        H, strt, PRU, W2Uf, d2, bu1, wu2f, bu2, out);
  } else {
    hipMemsetAsync(H, 0, (size_t)NN * 64 * sizeof(float), stream);
    k_edge_at<<<(NE + 255) / 256, 256, 0, stream>>>(idx, ef, B, c, wm2, bm2, PRA, H);
    k_update_at<<<(NN + 255) / 256, 256, 0, stream>>>(
        H, PRU, wu1, bu1, wu2, bu2, out);
  }
}

// Round 17
// 361.750 us; speedup vs baseline: 1.8144x; 1.0228x over previous
//
#include <hip/hip_runtime.h>

#define NN 100000
#define NE 1600000

typedef __attribute__((ext_vector_type(8))) short bf16x8;
typedef __attribute__((ext_vector_type(4))) float f32x4;

// ---------------------------------------------------------------------------
// Workspace layout in 4-byte units (~296 MB; proven available)
// ---------------------------------------------------------------------------
#define OFF_M    0                         // 128*128 folded (fallback)
#define OFF_B    (OFF_M + 16384)           // 32*64 (fallback)
#define OFF_C    (OFF_B + 2048)            // 64
#define OFF_W2U  (OFF_C + 64)              // 64*64 f32 (fallback)
#define OFF_D2   (OFF_W2U + 4096)          // 64
#define OFF_BFRG (OFF_D2 + 64)             // 4*64 uint4
#define OFF_MFRG (OFF_BFRG + 1024)         // 32*64 uint4
#define OFF_W2UF (OFF_MFRG + 8192)         // 8*64 uint4
#define OFF_WU2F (OFF_W2UF + 2048)         // 8*64 uint4
#define OFF_BSUM (OFF_WU2F + 2048)         // 128
#define OFF_BOFF (OFF_BSUM + 128)          // 128
#define OFF_PRA  (OFF_BOFF + 128)          // NN*64 f32 (fallback only)
#define OFF_PRAH (OFF_PRA + NN * 64)       // NN*32: PRA bf16
#define OFF_PRU  (OFF_PRAH + NN * 32)      // NN*64
#define OFF_H    (OFF_PRU + NN * 64)       // NN*64 (fallback agg); fast: Hb NN*32
#define OFF_HIST (OFF_H + NN * 64)         // NN
#define OFF_CUR  (OFF_HIST + NN)           // NN
#define OFF_STRT (OFF_CUR + NN)            // NN+1 (+pad)
#define OFF_HS   (OFF_STRT + NN + 4)       // NE*32 dwords (bf16 rows)
#define WS_UNITS (OFF_HS + NE * 32)

__device__ __forceinline__ unsigned bfr(float x) {
  unsigned u = __float_as_uint(x);
  return (u + 0x7fffu + ((u >> 16) & 1u)) >> 16;
}
__device__ __forceinline__ float bf2f(unsigned short h) {
  return __uint_as_float(((unsigned)h) << 16);
}
__device__ __forceinline__ unsigned addrelu1(unsigned qa, unsigned pb) {
  float lo = __uint_as_float((qa & 0xffffu) << 16) +
             __uint_as_float((pb & 0xffffu) << 16);
  float hi = __uint_as_float(qa & 0xffff0000u) +
             __uint_as_float(pb & 0xffff0000u);
  lo = fmaxf(lo, 0.f);
  hi = fmaxf(hi, 0.f);
  return bfr(lo) | (bfr(hi) << 16);
}
__device__ __forceinline__ uint4 addrelu4(uint4 q, uint4 p) {
  return make_uint4(addrelu1(q.x, p.x), addrelu1(q.y, p.y),
                    addrelu1(q.z, p.z), addrelu1(q.w, p.w));
}

// ---------------------------------------------------------------------------
// Weight folding + bf16 fragment packs (unchanged from round 16)
// ---------------------------------------------------------------------------
__global__ __launch_bounds__(256) void k_fold(
    const float* __restrict__ wn, const float* __restrict__ bn,
    const float* __restrict__ we, const float* __restrict__ be,
    const float* __restrict__ wm1, const float* __restrict__ bm1,
    const float* __restrict__ wm2, const float* __restrict__ bm2,
    const float* __restrict__ wu1, const float* __restrict__ wu2,
    float* __restrict__ M, float* __restrict__ B, float* __restrict__ c,
    float* __restrict__ W2U, float* __restrict__ d2,
    uint4* __restrict__ Bfrag, uint4* __restrict__ Mfrag,
    uint4* __restrict__ W2Uf, uint4* __restrict__ wu2f) {
  int t = blockIdx.x * 256 + threadIdx.x;
  if (t < 16384) {
    int k = t >> 7, j = t & 127;
    float acc;
    if (j < 64) {
      acc = 0.f;
      for (int h = 0; h < 64; ++h) acc += wn[k * 64 + h] * wm1[h * 64 + j];
    } else {
      acc = wu1[k * 64 + (j - 64)];
    }
    M[t] = acc;
  } else if (t < 16384 + 2048) {
    int u = t - 16384;
    int k = u >> 6, j = u & 63;
    float acc = 0.f;
    for (int h = 0; h < 64; ++h) acc += we[k * 64 + h] * wm1[(64 + h) * 64 + j];
    B[u] = acc;
  } else if (t < 16384 + 2048 + 64) {
    int j = t - (16384 + 2048);
    float acc = bm1[j];
    for (int h = 0; h < 64; ++h)
      acc += bn[h] * wm1[h * 64 + j] + be[h] * wm1[(64 + h) * 64 + j];
    c[j] = acc;
  } else if (t < 16384 + 2048 + 64 + 4096) {
    int u = t - (16384 + 2048 + 64);
    int k = u >> 6, j = u & 63;
    float acc = 0.f;
    for (int h = 0; h < 64; ++h) acc += wm2[k * 64 + h] * wu1[(128 + h) * 64 + j];
    W2U[u] = acc;
  } else if (t < 16384 + 2048 + 64 + 4096 + 64) {
    int j = t - (16384 + 2048 + 64 + 4096);
    float acc = 0.f;
    for (int h = 0; h < 64; ++h) acc += bm2[h] * wu1[(128 + h) * 64 + j];
    d2[j] = acc;
  } else if (t < 16384 + 2048 + 64 + 4096 + 64 + 256) {
    int u = t - (16384 + 2048 + 64 + 4096 + 64);
    int jb = u >> 6, l = u & 63;
    int g = l >> 4, n = l & 15;
    unsigned s[8];
#pragma unroll
    for (int i = 0; i < 8; ++i) {
      int k = g * 8 + i;
      int j = jb * 16 + n;
      float acc = 0.f;
      for (int h = 0; h < 64; ++h)
        acc += we[k * 64 + h] * wm1[(64 + h) * 64 + j];
      s[i] = bfr(acc);
    }
    Bfrag[jb * 64 + l] = make_uint4(s[0] | (s[1] << 16), s[2] | (s[3] << 16),
                                    s[4] | (s[5] << 16), s[6] | (s[7] << 16));
  } else if (t < 16384 + 2048 + 64 + 4096 + 64 + 256 + 2048) {
    int u = t - (16384 + 2048 + 64 + 4096 + 64 + 256);
    int jb = u >> 8, kb = (u >> 6) & 3, l = u & 63;
    int g = l >> 4, n = l & 15;
    int j = jb * 16 + n;
    unsigned s[8];
#pragma unroll
    for (int i = 0; i < 8; ++i) {
      int k = kb * 32 + g * 8 + i;
      float acc;
      if (j < 64) {
        acc = 0.f;
        for (int h = 0; h < 64; ++h) acc += wn[k * 64 + h] * wm1[h * 64 + j];
      } else {
        acc = wu1[k * 64 + (j - 64)];
      }
      s[i] = bfr(acc);
    }
    Mfrag[(jb * 4 + kb) * 64 + l] =
        make_uint4(s[0] | (s[1] << 16), s[2] | (s[3] << 16),
                   s[4] | (s[5] << 16), s[6] | (s[7] << 16));
  } else if (t < 16384 + 2048 + 64 + 4096 + 64 + 256 + 2048 + 512) {
    int u = t - (16384 + 2048 + 64 + 4096 + 64 + 256 + 2048);
    int jk = u >> 6, l = u & 63;
    int jb = jk >> 1, kb = jk & 1;
    int g = l >> 4, n = l & 15;
    int j = jb * 16 + n;
    unsigned s[8];
#pragma unroll
    for (int i = 0; i < 8; ++i) {
      int k = kb * 32 + g * 8 + i;
      float acc = 0.f;
      for (int h = 0; h < 64; ++h)
        acc += wm2[k * 64 + h] * wu1[(128 + h) * 64 + j];
      s[i] = bfr(acc);
    }
    W2Uf[jk * 64 + l] = make_uint4(s[0] | (s[1] << 16), s[2] | (s[3] << 16),
                                   s[4] | (s[5] << 16), s[6] | (s[7] << 16));
  } else if (t < 16384 + 2048 + 64 + 4096 + 64 + 256 + 2048 + 512 + 512) {
    int u = t - (16384 + 2048 + 64 + 4096 + 64 + 256 + 2048 + 512);
    int jk = u >> 6, l = u & 63;
    int jb = jk >> 1, kb = jk & 1;
    int g = l >> 4, n = l & 15;
    unsigned s[8];
#pragma unroll
    for (int i = 0; i < 8; ++i)
      s[i] = bfr(wu2[(size_t)(kb * 32 + g * 8 + i) * 64 + jb * 16 + n]);
    wu2f[jk * 64 + l] = make_uint4(s[0] | (s[1] << 16), s[2] | (s[3] << 16),
                                   s[4] | (s[5] << 16), s[6] | (s[7] << 16));
  }
}

// ---------------------------------------------------------------------------
// k_node2: MFMA node precompute. Emits PRAh (bf16, LDS-transposed burst) +
// PRU f32; PRA f32 only when writePRA!=0 (fallback path).
// ---------------------------------------------------------------------------
__global__ __launch_bounds__(256) void k_node2(
    const float* __restrict__ nf, const uint4* __restrict__ Mfrag,
    float* __restrict__ PRA, uint4* __restrict__ PRAh,
    float* __restrict__ PRU, int writePRA) {
  __shared__ unsigned short ldsP[4][16 * 72];
  int wib = threadIdx.x >> 6;
  int lane = threadIdx.x & 63;
  int tile = blockIdx.x * 4 + wib;
  if (tile >= NN / 16) return;
  int m = lane & 15, g = lane >> 4;
  int node = tile * 16 + m;

  bf16x8 a[4];
#pragma unroll
  for (int kb = 0; kb < 4; ++kb) {
    const float* __restrict__ rp = &nf[(size_t)node * 128 + kb * 32 + g * 8];
    float4 f0 = *(const float4*)rp;
    float4 f1 = *(const float4*)(rp + 4);
    bf16x8 v;
    v[0] = (short)bfr(f0.x); v[1] = (short)bfr(f0.y);
    v[2] = (short)bfr(f0.z); v[3] = (short)bfr(f0.w);
    v[4] = (short)bfr(f1.x); v[5] = (short)bfr(f1.y);
    v[6] = (short)bfr(f1.z); v[7] = (short)bfr(f1.w);
    a[kb] = v;
  }

  const bf16x8* __restrict__ mfp = (const bf16x8*)Mfrag;
  unsigned short* __restrict__ lp = &ldsP[wib][0];
#pragma unroll
  for (int jb = 0; jb < 8; ++jb) {
    f32x4 acc = {0.f, 0.f, 0.f, 0.f};
    acc = __builtin_amdgcn_mfma_f32_16x16x32_bf16(a[0], mfp[(jb * 4 + 0) * 64 + lane], acc, 0, 0, 0);
    acc = __builtin_amdgcn_mfma_f32_16x16x32_bf16(a[1], mfp[(jb * 4 + 1) * 64 + lane], acc, 0, 0, 0);
    acc = __builtin_amdgcn_mfma_f32_16x16x32_bf16(a[2], mfp[(jb * 4 + 2) * 64 + lane], acc, 0, 0, 0);
    acc = __builtin_amdgcn_mfma_f32_16x16x32_bf16(a[3], mfp[(jb * 4 + 3) * 64 + lane], acc, 0, 0, 0);
    int col = (jb & 3) * 16 + m;
    if (jb < 4) {
      // PRA quadrant -> LDS bf16 (for transposed burst store)
#pragma unroll
      for (int r = 0; r < 4; ++r)
        lp[(g * 4 + r) * 72 + col] = (unsigned short)bfr(acc[r]);
      if (writePRA) {
#pragma unroll
        for (int r = 0; r < 4; ++r)
          PRA[(size_t)(tile * 16 + g * 4 + r) * 64 + col] = acc[r];
      }
    } else {
#pragma unroll
      for (int r = 0; r < 4; ++r)
        PRU[(size_t)(tile * 16 + g * 4 + r) * 64 + col] = acc[r];
    }
  }
  __syncthreads();

  int m2 = lane >> 2, lo = lane & 3;
  uint4 w0 = *(const uint4*)&ldsP[wib][m2 * 72 + lo * 16];
  uint4 w1 = *(const uint4*)&ldsP[wib][m2 * 72 + lo * 16 + 8];
  uint4* __restrict__ pp = &PRAh[(size_t)(tile * 16 + m2) * 8];
  pp[lo * 2] = w0;
  pp[lo * 2 + 1] = w1;
}

// ---------------------------------------------------------------------------
// Counting sort: hist -> 3-phase scan
// ---------------------------------------------------------------------------
__global__ __launch_bounds__(256) void k_hist(const int* __restrict__ idx,
                                              int* __restrict__ hist) {
  int e = blockIdx.x * 256 + threadIdx.x;
  if (e < NE) atomicAdd(&hist[idx[NE + e]], 1);
}

__global__ __launch_bounds__(1024) void k_scanA(const int* __restrict__ hist,
                                                int* __restrict__ strt,
                                                int* __restrict__ bsum) {
  __shared__ int lds[1024];
  int t = threadIdx.x;
  int i = blockIdx.x * 1024 + t;
  int v = (i < NN) ? hist[i] : 0;
  lds[t] = v;
  __syncthreads();
  for (int off = 1; off < 1024; off <<= 1) {
    int u = (t >= off) ? lds[t - off] : 0;
    __syncthreads();
    lds[t] += u;
    __syncthreads();
  }
  if (i < NN) strt[i] = lds[t] - v;
  if (t == 1023) bsum[blockIdx.x] = lds[1023];
}

__global__ __launch_bounds__(128) void k_scanB(const int* __restrict__ bsum,
                                               int* __restrict__ boff,
                                               int* __restrict__ strt,
                                               int nblocks) {
  __shared__ int lds[128];
  int t = threadIdx.x;
  int v = (t < nblocks) ? bsum[t] : 0;
  lds[t] = v;
  __syncthreads();
  for (int off = 1; off < 128; off <<= 1) {
    int u = (t >= off) ? lds[t - off] : 0;
    __syncthreads();
    lds[t] += u;
    __syncthreads();
  }
  if (t < nblocks) boff[t] = lds[t] - v;
  if (t == 127) strt[NN] = lds[127];
}

__global__ __launch_bounds__(1024) void k_scanC(int* __restrict__ strt,
                                                const int* __restrict__ boff) {
  int i = blockIdx.x * 1024 + threadIdx.x;
  if (i < NN) strt[i] += boff[blockIdx.x];
}

// ---------------------------------------------------------------------------
// k_msgh: wave per 16-edge tile. PRAh loads issued at kernel entry (src from
// idx directly, no LDS round-trip) so their latency hides under the MFMA
// phase. MFMA q=ef@B + bias -> LDS transpose -> add PRAh, relu, 128B burst
// store to dst-sorted slot.
// ---------------------------------------------------------------------------
__global__ __launch_bounds__(256) void k_msgh(
    const int* __restrict__ idx, const int* __restrict__ strt,
    int* __restrict__ cursor, const float* __restrict__ ef,
    const uint4* __restrict__ Bfrag, const float* __restrict__ c,
    const uint4* __restrict__ PRAh, unsigned short* __restrict__ hS) {
  __shared__ unsigned short ldsQ[4][16 * 72];
  __shared__ int slotA[4][16];
  int wib = threadIdx.x >> 6;
  int lane = threadIdx.x & 63;
  int m = lane & 15, g = lane >> 4;
  int tile = blockIdx.x * 4 + wib;

  // early: issue PRAh loads for this lane's phase-6 edge (m2 = lane>>2)
  int m2 = lane >> 2, lo = lane & 3;
  int src6 = idx[tile * 16 + m2];
  uint4 p0 = PRAh[(size_t)src6 * 8 + lo * 2];
  uint4 p1 = PRAh[(size_t)src6 * 8 + lo * 2 + 1];

  // slot assignment (one lane per edge)
  if (lane < 16) {
    int e = tile * 16 + m;
    int dst = idx[NE + e];
    int pos = atomicAdd(&cursor[dst], 1);
    slotA[wib][m] = strt[dst] + pos;
  }

  const float* __restrict__ rp = &ef[(size_t)(tile * 16 + m) * 32 + g * 8];
  float4 f0 = *(const float4*)rp;
  float4 f1 = *(const float4*)(rp + 4);
  bf16x8 a;
  a[0] = (short)bfr(f0.x); a[1] = (short)bfr(f0.y);
  a[2] = (short)bfr(f0.z); a[3] = (short)bfr(f0.w);
  a[4] = (short)bfr(f1.x); a[5] = (short)bfr(f1.y);
  a[6] = (short)bfr(f1.z); a[7] = (short)bfr(f1.w);

  const bf16x8* __restrict__ bfp = (const bf16x8*)Bfrag;
  bf16x8 b0 = bfp[0 * 64 + lane];
  bf16x8 b1 = bfp[1 * 64 + lane];
  bf16x8 b2 = bfp[2 * 64 + lane];
  bf16x8 b3 = bfp[3 * 64 + lane];
  float cl0 = c[0 * 16 + m], cl1 = c[1 * 16 + m];
  float cl2 = c[2 * 16 + m], cl3 = c[3 * 16 + m];

  f32x4 z = {0.f, 0.f, 0.f, 0.f};
  f32x4 q0 = __builtin_amdgcn_mfma_f32_16x16x32_bf16(a, b0, z, 0, 0, 0);
  f32x4 q1 = __builtin_amdgcn_mfma_f32_16x16x32_bf16(a, b1, z, 0, 0, 0);
  f32x4 q2 = __builtin_amdgcn_mfma_f32_16x16x32_bf16(a, b2, z, 0, 0, 0);
  f32x4 q3 = __builtin_amdgcn_mfma_f32_16x16x32_bf16(a, b3, z, 0, 0, 0);

  unsigned short* __restrict__ lq = &ldsQ[wib][0];
#pragma unroll
  for (int r = 0; r < 4; ++r) {
    int mp = g * 4 + r;
    lq[mp * 72 + 0 * 16 + m] = (unsigned short)bfr(q0[r] + cl0);
    lq[mp * 72 + 1 * 16 + m] = (unsigned short)bfr(q1[r] + cl1);
    lq[mp * 72 + 2 * 16 + m] = (unsigned short)bfr(q2[r] + cl2);
    lq[mp * 72 + 3 * 16 + m] = (unsigned short)bfr(q3[r] + cl3);
  }
  __syncthreads();

  uint4 w0 = *(const uint4*)&ldsQ[wib][m2 * 72 + lo * 16];
  uint4 w1 = *(const uint4*)&ldsQ[wib][m2 * 72 + lo * 16 + 8];
  int slot = slotA[wib][m2];
  uint4 h0 = addrelu4(w0, p0);
  uint4 h1 = addrelu4(w1, p1);
  uint4* __restrict__ qp = (uint4*)(hS + (size_t)slot * 64);
  qp[lo * 2] = h0;
  qp[lo * 2 + 1] = h1;
}

// ---------------------------------------------------------------------------
// k_sum: streaming segment-sum; outputs bf16-packed Hb (pair-pack via shfl).
// ---------------------------------------------------------------------------
__global__ __launch_bounds__(256) void k_sum(
    const unsigned short* __restrict__ hS, const int* __restrict__ strt,
    unsigned* __restrict__ Hb) {
  int wib = threadIdx.x >> 6;
  int lane = threadIdx.x & 63;
  int n = blockIdx.x * 4 + wib;
  if (n >= NN) return;
  int s0 = strt[n], s1 = strt[n + 1];
  float acc = 0.f;
  int s = s0;
  for (; s + 4 <= s1; s += 4) {
    unsigned short a0 = hS[(size_t)(s + 0) * 64 + lane];
    unsigned short a1 = hS[(size_t)(s + 1) * 64 + lane];
    unsigned short a2 = hS[(size_t)(s + 2) * 64 + lane];
    unsigned short a3 = hS[(size_t)(s + 3) * 64 + lane];
    acc += (bf2f(a0) + bf2f(a1)) + (bf2f(a2) + bf2f(a3));
  }
  for (; s < s1; ++s) acc += bf2f(hS[(size_t)s * 64 + lane]);
  float other = __shfl_xor(acc, 1);
  if ((lane & 1) == 0)
    Hb[(size_t)n * 32 + (lane >> 1)] = bfr(acc) | (bfr(other) << 16);
}

// ---------------------------------------------------------------------------
// k_update5: MFMA update MLP; H read directly as bf16 frags from Hb.
// ---------------------------------------------------------------------------
__global__ __launch_bounds__(256) void k_update5(
    const unsigned* __restrict__ Hb, const int* __restrict__ strt,
    const float* __restrict__ PRU,
    const uint4* __restrict__ W2Uf, const float* __restrict__ d2,
    const float* __restrict__ bu1,
    const uint4* __restrict__ wu2f, const float* __restrict__ bu2,
    float* __restrict__ out) {
  __shared__ unsigned short ldsH[4][16 * 72];
  int wib = threadIdx.x >> 6;
  int lane = threadIdx.x & 63;
  int tile = blockIdx.x * 4 + wib;
  if (tile >= NN / 16) return;
  int m = lane & 15, g = lane >> 4;
  int node = tile * 16 + m;

  bf16x8 ah[2];
  ah[0] = *(const bf16x8*)&Hb[(size_t)node * 32 + 0 * 16 + g * 4];
  ah[1] = *(const bf16x8*)&Hb[(size_t)node * 32 + 1 * 16 + g * 4];

  float deg[4];
#pragma unroll
  for (int r = 0; r < 4; ++r) {
    int row = tile * 16 + g * 4 + r;
    deg[r] = (float)(strt[row + 1] - strt[row]);
  }

  const bf16x8* __restrict__ w2p = (const bf16x8*)W2Uf;
  const bf16x8* __restrict__ wup = (const bf16x8*)wu2f;
  unsigned short* __restrict__ lh = &ldsH[wib][0];

#pragma unroll
  for (int jb = 0; jb < 4; ++jb) {
    f32x4 acc = {0.f, 0.f, 0.f, 0.f};
    acc = __builtin_amdgcn_mfma_f32_16x16x32_bf16(ah[0], w2p[(jb * 2 + 0) * 64 + lane], acc, 0, 0, 0);
    acc = __builtin_amdgcn_mfma_f32_16x16x32_bf16(ah[1], w2p[(jb * 2 + 1) * 64 + lane], acc, 0, 0, 0);
    int col = jb * 16 + m;
    float dc = d2[col], bc = bu1[col];
#pragma unroll
    for (int r = 0; r < 4; ++r) {
      int row = tile * 16 + g * 4 + r;
      float pre = acc[r] + PRU[(size_t)row * 64 + col] + deg[r] * dc + bc;
      lh[(g * 4 + r) * 72 + col] = (unsigned short)bfr(fmaxf(pre, 0.f));
    }
  }
  __syncthreads();

  bf16x8 a2[2];
  a2[0] = *(const bf16x8*)&lh[m * 72 + 0 * 32 + g * 8];
  a2[1] = *(const bf16x8*)&lh[m * 72 + 1 * 32 + g * 8];
#pragma unroll
  for (int jb = 0; jb < 4; ++jb) {
    f32x4 acc = {0.f, 0.f, 0.f, 0.f};
    acc = __builtin_amdgcn_mfma_f32_16x16x32_bf16(a2[0], wup[(jb * 2 + 0) * 64 + lane], acc, 0, 0, 0);
    acc = __builtin_amdgcn_mfma_f32_16x16x32_bf16(a2[1], wup[(jb * 2 + 1) * 64 + lane], acc, 0, 0, 0);
    int col = jb * 16 + m;
    float bc = bu2[col];
#pragma unroll
    for (int r = 0; r < 4; ++r) {
      int row = tile * 16 + g * 4 + r;
      out[(size_t)row * 64 + col] = acc[r] + bc;
    }
  }
}

// ---------------------------------------------------------------------------
// Fallback (ws too small): round-1 atomic scatter path
// ---------------------------------------------------------------------------
__global__ __launch_bounds__(256) void k_edge_at(
    const int* __restrict__ idx, const float* __restrict__ ef,
    const float* __restrict__ B, const float* __restrict__ c,
    const float* __restrict__ wm2, const float* __restrict__ bm2,
    const float* __restrict__ PRA, float* __restrict__ agg) {
  int e = blockIdx.x * 256 + threadIdx.x;
  if (e >= NE) return;
  int src = idx[e];
  int dst = idx[NE + e];
  float efr[32];
#pragma unroll
  for (int k = 0; k < 32; k += 4)
    *(float4*)&efr[k] = *(const float4*)&ef[(size_t)e * 32 + k];
  float m[64];
#pragma unroll
  for (int o = 0; o < 64; ++o) m[o] = bm2[o];
  const float* __restrict__ prs = &PRA[(size_t)src * 64];
#pragma unroll 1
  for (int jc = 0; jc < 64; jc += 16) {
    float q[16];
#pragma unroll
    for (int jj = 0; jj < 16; ++jj) q[jj] = c[jc + jj];
#pragma unroll
    for (int k = 0; k < 32; ++k) {
      float ev = efr[k];
#pragma unroll
      for (int jj = 0; jj < 16; ++jj) q[jj] += ev * B[k * 64 + jc + jj];
    }
#pragma unroll
    for (int jj = 0; jj < 16; ++jj) {
      float h = fmaxf(prs[jc + jj] + q[jj], 0.f);
#pragma unroll
      for (int o = 0; o < 64; ++o) m[o] += h * wm2[(jc + jj) * 64 + o];
    }
  }
  float* __restrict__ ap = &agg[(size_t)dst * 64];
#pragma unroll
  for (int o = 0; o < 64; ++o) atomicAdd(&ap[o], m[o]);
}

__global__ __launch_bounds__(256) void k_update_at(
    const float* __restrict__ agg, const float* __restrict__ PRU,
    const float* __restrict__ wu1, const float* __restrict__ bu1,
    const float* __restrict__ wu2, const float* __restrict__ bu2,
    float* __restrict__ out) {
  int n = blockIdx.x * 256 + threadIdx.x;
  if (n >= NN) return;
  float ar[64];
#pragma unroll
  for (int k = 0; k < 64; k += 4)
    *(float4*)&ar[k] = *(const float4*)&agg[(size_t)n * 64 + k];
  float acc[64];
#pragma unroll
  for (int o = 0; o < 64; ++o) acc[o] = bu2[o];
  const float* __restrict__ prs = &PRU[(size_t)n * 64];
#pragma unroll 1
  for (int jc = 0; jc < 64; jc += 16) {
    float q[16];
#pragma unroll
    for (int jj = 0; jj < 16; ++jj) q[jj] = bu1[jc + jj];
#pragma unroll
    for (int k = 0; k < 64; ++k) {
      float av = ar[k];
#pragma unroll
      for (int jj = 0; jj < 16; ++jj) q[jj] += av * wu1[(128 + k) * 64 + jc + jj];
    }
#pragma unroll
    for (int jj = 0; jj < 16; ++jj) {
      float h = fmaxf(prs[jc + jj] + q[jj], 0.f);
#pragma unroll
      for (int o = 0; o < 64; ++o) acc[o] += h * wu2[(jc + jj) * 64 + o];
    }
  }
#pragma unroll
  for (int o = 0; o < 64; o += 4)
    *(float4*)&out[(size_t)n * 64 + o] = make_float4(acc[o], acc[o + 1], acc[o + 2], acc[o + 3]);
}

extern "C" void kernel_launch(void* const* d_in, const int* in_sizes, int n_in,
                              void* d_out, int out_size, void* d_ws, size_t ws_size,
                              hipStream_t stream) {
  const float* nf  = (const float*)d_in[0];
  const int*   idx = (const int*)d_in[1];
  const float* ef  = (const float*)d_in[2];
  const float* wn  = (const float*)d_in[3];
  const float* bn  = (const float*)d_in[4];
  const float* we  = (const float*)d_in[5];
  const float* be  = (const float*)d_in[6];
  const float* wm1 = (const float*)d_in[7];
  const float* bm1 = (const float*)d_in[8];
  const float* wm2 = (const float*)d_in[9];
  const float* bm2 = (const float*)d_in[10];
  const float* wu1 = (const float*)d_in[11];
  const float* bu1 = (const float*)d_in[12];
  const float* wu2 = (const float*)d_in[13];
  const float* bu2 = (const float*)d_in[14];
  float* out = (float*)d_out;

  float* ws   = (float*)d_ws;
  float* M    = ws + OFF_M;
  float* B    = ws + OFF_B;
  float* c    = ws + OFF_C;
  float* W2U  = ws + OFF_W2U;
  float* d2   = ws + OFF_D2;
  uint4* Bfrg = (uint4*)(ws + OFF_BFRG);
  uint4* Mfrg = (uint4*)(ws + OFF_MFRG);
  uint4* W2Uf = (uint4*)(ws + OFF_W2UF);
  uint4* wu2f = (uint4*)(ws + OFF_WU2F);
  int*   bsum = (int*)(ws + OFF_BSUM);
  int*   boff = (int*)(ws + OFF_BOFF);
  float* PRA  = ws + OFF_PRA;
  uint4* PRAh = (uint4*)(ws + OFF_PRAH);
  float* PRU  = ws + OFF_PRU;
  float* H    = ws + OFF_H;                 // fallback agg
  unsigned* Hb = (unsigned*)(ws + OFF_H);   // fast-path bf16 H
  int*   hist = (int*)(ws + OFF_HIST);
  int*   cur  = (int*)(ws + OFF_CUR);
  int*   strt = (int*)(ws + OFF_STRT);
  unsigned short* hS = (unsigned short*)(ws + OFF_HS);

  const int SCAN_BLOCKS = (NN + 1023) / 1024;  // 98
  const int FOLD_THREADS = 16384 + 2048 + 64 + 4096 + 64 + 256 + 2048 + 512 + 512;
  const int NTILE = NN / 16;  // 6250

  int fast = (ws_size >= (size_t)WS_UNITS * 4);

  k_fold<<<(FOLD_THREADS + 255) / 256, 256, 0, stream>>>(
      wn, bn, we, be, wm1, bm1, wm2, bm2, wu1, wu2,
      M, B, c, W2U, d2, Bfrg, Mfrg, W2Uf, wu2f);
  k_node2<<<(NTILE + 3) / 4, 256, 0, stream>>>(nf, Mfrg, PRA, PRAh, PRU,
                                               fast ? 0 : 1);

  if (fast) {
    hipMemsetAsync(hist, 0, (size_t)2 * NN * sizeof(int), stream);
    k_hist<<<(NE + 255) / 256, 256, 0, stream>>>(idx, hist);
    k_scanA<<<SCAN_BLOCKS, 1024, 0, stream>>>(hist, strt, bsum);
    k_scanB<<<1, 128, 0, stream>>>(bsum, boff, strt, SCAN_BLOCKS);
    k_scanC<<<SCAN_BLOCKS, 1024, 0, stream>>>(strt, boff);
    k_msgh<<<NE / 16 / 4, 256, 0, stream>>>(idx, strt, cur, ef, Bfrg, c,
                                            PRAh, hS);
    k_sum<<<(NN + 3) / 4, 256, 0, stream>>>(hS, strt, Hb);
    k_update5<<<(NTILE + 3) / 4, 256, 0, stream>>>(
        Hb, strt, PRU, W2Uf, d2, bu1, wu2f, bu2, out);
  } else {
    hipMemsetAsync(H, 0, (size_t)NN * 64 * sizeof(float), stream);
    k_edge_at<<<(NE + 255) / 256, 256, 0, stream>>>(idx, ef, B, c, wm2, bm2, PRA, H);
    k_update_at<<<(NN + 255) / 256, 256, 0, stream>>>(
        H, PRU, wu1, bu1, wu2, bu2, out);
  }
}

// Round 18
// 360.314 us; speedup vs baseline: 1.8217x; 1.0040x over previous
//
#include <hip/hip_runtime.h>

#define NN 100000
#define NE 1600000

typedef __attribute__((ext_vector_type(8))) short bf16x8;
typedef __attribute__((ext_vector_type(4))) float f32x4;

// ---------------------------------------------------------------------------
// Workspace layout in 4-byte units (~296 MB; proven available)
// ---------------------------------------------------------------------------
#define OFF_M    0                         // 128*128 folded (fallback)
#define OFF_B    (OFF_M + 16384)           // 32*64 (fallback)
#define OFF_C    (OFF_B + 2048)            // 64
#define OFF_W2U  (OFF_C + 64)              // 64*64 f32 (fallback)
#define OFF_D2   (OFF_W2U + 4096)          // 64
#define OFF_BFRG (OFF_D2 + 64)             // 4*64 uint4
#define OFF_MFRG (OFF_BFRG + 1024)         // 32*64 uint4
#define OFF_W2UF (OFF_MFRG + 8192)         // 8*64 uint4
#define OFF_WU2F (OFF_W2UF + 2048)         // 8*64 uint4
#define OFF_BSUM (OFF_WU2F + 2048)         // 128
#define OFF_BOFF (OFF_BSUM + 128)          // 128
#define OFF_PRA  (OFF_BOFF + 128)          // NN*64 f32 (fallback only)
#define OFF_PRAH (OFF_PRA + NN * 64)       // NN*32: PRA bf16
#define OFF_PRU  (OFF_PRAH + NN * 32)      // NN*64
#define OFF_H    (OFF_PRU + NN * 64)       // NN*64 (fallback agg); fast: Hb NN*32
#define OFF_HIST (OFF_H + NN * 64)         // NN
#define OFF_CUR  (OFF_HIST + NN)           // NN
#define OFF_STRT (OFF_CUR + NN)            // NN+1 (+pad)
#define OFF_HS   (OFF_STRT + NN + 4)       // NE*32 dwords (bf16 rows)
#define WS_UNITS (OFF_HS + NE * 32)

__device__ __forceinline__ unsigned bfr(float x) {
  unsigned u = __float_as_uint(x);
  return (u + 0x7fffu + ((u >> 16) & 1u)) >> 16;
}
__device__ __forceinline__ float bf2f(unsigned short h) {
  return __uint_as_float(((unsigned)h) << 16);
}
__device__ __forceinline__ unsigned addrelu1(unsigned qa, unsigned pb) {
  float lo = __uint_as_float((qa & 0xffffu) << 16) +
             __uint_as_float((pb & 0xffffu) << 16);
  float hi = __uint_as_float(qa & 0xffff0000u) +
             __uint_as_float(pb & 0xffff0000u);
  lo = fmaxf(lo, 0.f);
  hi = fmaxf(hi, 0.f);
  return bfr(lo) | (bfr(hi) << 16);
}
__device__ __forceinline__ uint4 addrelu4(uint4 q, uint4 p) {
  return make_uint4(addrelu1(q.x, p.x), addrelu1(q.y, p.y),
                    addrelu1(q.z, p.z), addrelu1(q.w, p.w));
}

// ---------------------------------------------------------------------------
// Weight folding + bf16 fragment packs (unchanged)
// ---------------------------------------------------------------------------
__global__ __launch_bounds__(256) void k_fold(
    const float* __restrict__ wn, const float* __restrict__ bn,
    const float* __restrict__ we, const float* __restrict__ be,
    const float* __restrict__ wm1, const float* __restrict__ bm1,
    const float* __restrict__ wm2, const float* __restrict__ bm2,
    const float* __restrict__ wu1, const float* __restrict__ wu2,
    float* __restrict__ M, float* __restrict__ B, float* __restrict__ c,
    float* __restrict__ W2U, float* __restrict__ d2,
    uint4* __restrict__ Bfrag, uint4* __restrict__ Mfrag,
    uint4* __restrict__ W2Uf, uint4* __restrict__ wu2f) {
  int t = blockIdx.x * 256 + threadIdx.x;
  if (t < 16384) {
    int k = t >> 7, j = t & 127;
    float acc;
    if (j < 64) {
      acc = 0.f;
      for (int h = 0; h < 64; ++h) acc += wn[k * 64 + h] * wm1[h * 64 + j];
    } else {
      acc = wu1[k * 64 + (j - 64)];
    }
    M[t] = acc;
  } else if (t < 16384 + 2048) {
    int u = t - 16384;
    int k = u >> 6, j = u & 63;
    float acc = 0.f;
    for (int h = 0; h < 64; ++h) acc += we[k * 64 + h] * wm1[(64 + h) * 64 + j];
    B[u] = acc;
  } else if (t < 16384 + 2048 + 64) {
    int j = t - (16384 + 2048);
    float acc = bm1[j];
    for (int h = 0; h < 64; ++h)
      acc += bn[h] * wm1[h * 64 + j] + be[h] * wm1[(64 + h) * 64 + j];
    c[j] = acc;
  } else if (t < 16384 + 2048 + 64 + 4096) {
    int u = t - (16384 + 2048 + 64);
    int k = u >> 6, j = u & 63;
    float acc = 0.f;
    for (int h = 0; h < 64; ++h) acc += wm2[k * 64 + h] * wu1[(128 + h) * 64 + j];
    W2U[u] = acc;
  } else if (t < 16384 + 2048 + 64 + 4096 + 64) {
    int j = t - (16384 + 2048 + 64 + 4096);
    float acc = 0.f;
    for (int h = 0; h < 64; ++h) acc += bm2[h] * wu1[(128 + h) * 64 + j];
    d2[j] = acc;
  } else if (t < 16384 + 2048 + 64 + 4096 + 64 + 256) {
    int u = t - (16384 + 2048 + 64 + 4096 + 64);
    int jb = u >> 6, l = u & 63;
    int g = l >> 4, n = l & 15;
    unsigned s[8];
#pragma unroll
    for (int i = 0; i < 8; ++i) {
      int k = g * 8 + i;
      int j = jb * 16 + n;
      float acc = 0.f;
      for (int h = 0; h < 64; ++h)
        acc += we[k * 64 + h] * wm1[(64 + h) * 64 + j];
      s[i] = bfr(acc);
    }
    Bfrag[jb * 64 + l] = make_uint4(s[0] | (s[1] << 16), s[2] | (s[3] << 16),
                                    s[4] | (s[5] << 16), s[6] | (s[7] << 16));
  } else if (t < 16384 + 2048 + 64 + 4096 + 64 + 256 + 2048) {
    int u = t - (16384 + 2048 + 64 + 4096 + 64 + 256);
    int jb = u >> 8, kb = (u >> 6) & 3, l = u & 63;
    int g = l >> 4, n = l & 15;
    int j = jb * 16 + n;
    unsigned s[8];
#pragma unroll
    for (int i = 0; i < 8; ++i) {
      int k = kb * 32 + g * 8 + i;
      float acc;
      if (j < 64) {
        acc = 0.f;
        for (int h = 0; h < 64; ++h) acc += wn[k * 64 + h] * wm1[h * 64 + j];
      } else {
        acc = wu1[k * 64 + (j - 64)];
      }
      s[i] = bfr(acc);
    }
    Mfrag[(jb * 4 + kb) * 64 + l] =
        make_uint4(s[0] | (s[1] << 16), s[2] | (s[3] << 16),
                   s[4] | (s[5] << 16), s[6] | (s[7] << 16));
  } else if (t < 16384 + 2048 + 64 + 4096 + 64 + 256 + 2048 + 512) {
    int u = t - (16384 + 2048 + 64 + 4096 + 64 + 256 + 2048);
    int jk = u >> 6, l = u & 63;
    int jb = jk >> 1, kb = jk & 1;
    int g = l >> 4, n = l & 15;
    int j = jb * 16 + n;
    unsigned s[8];
#pragma unroll
    for (int i = 0; i < 8; ++i) {
      int k = kb * 32 + g * 8 + i;
      float acc = 0.f;
      for (int h = 0; h < 64; ++h)
        acc += wm2[k * 64 + h] * wu1[(128 + h) * 64 + j];
      s[i] = bfr(acc);
    }
    W2Uf[jk * 64 + l] = make_uint4(s[0] | (s[1] << 16), s[2] | (s[3] << 16),
                                   s[4] | (s[5] << 16), s[6] | (s[7] << 16));
  } else if (t < 16384 + 2048 + 64 + 4096 + 64 + 256 + 2048 + 512 + 512) {
    int u = t - (16384 + 2048 + 64 + 4096 + 64 + 256 + 2048 + 512);
    int jk = u >> 6, l = u & 63;
    int jb = jk >> 1, kb = jk & 1;
    int g = l >> 4, n = l & 15;
    unsigned s[8];
#pragma unroll
    for (int i = 0; i < 8; ++i)
      s[i] = bfr(wu2[(size_t)(kb * 32 + g * 8 + i) * 64 + jb * 16 + n]);
    wu2f[jk * 64 + l] = make_uint4(s[0] | (s[1] << 16), s[2] | (s[3] << 16),
                                   s[4] | (s[5] << 16), s[6] | (s[7] << 16));
  }
}

// ---------------------------------------------------------------------------
// k_node2: MFMA node precompute -> PRAh (bf16 transposed burst) + PRU f32.
// Phase-2 bursts now fully contiguous per 64B sector: pp[lo] then pp[4+lo].
// ---------------------------------------------------------------------------
__global__ __launch_bounds__(256) void k_node2(
    const float* __restrict__ nf, const uint4* __restrict__ Mfrag,
    float* __restrict__ PRA, uint4* __restrict__ PRAh,
    float* __restrict__ PRU, int writePRA) {
  __shared__ unsigned short ldsP[4][16 * 72];
  int wib = threadIdx.x >> 6;
  int lane = threadIdx.x & 63;
  int tile = blockIdx.x * 4 + wib;
  if (tile >= NN / 16) return;
  int m = lane & 15, g = lane >> 4;
  int node = tile * 16 + m;

  bf16x8 a[4];
#pragma unroll
  for (int kb = 0; kb < 4; ++kb) {
    const float* __restrict__ rp = &nf[(size_t)node * 128 + kb * 32 + g * 8];
    float4 f0 = *(const float4*)rp;
    float4 f1 = *(const float4*)(rp + 4);
    bf16x8 v;
    v[0] = (short)bfr(f0.x); v[1] = (short)bfr(f0.y);
    v[2] = (short)bfr(f0.z); v[3] = (short)bfr(f0.w);
    v[4] = (short)bfr(f1.x); v[5] = (short)bfr(f1.y);
    v[6] = (short)bfr(f1.z); v[7] = (short)bfr(f1.w);
    a[kb] = v;
  }

  const bf16x8* __restrict__ mfp = (const bf16x8*)Mfrag;
  unsigned short* __restrict__ lp = &ldsP[wib][0];
#pragma unroll
  for (int jb = 0; jb < 8; ++jb) {
    f32x4 acc = {0.f, 0.f, 0.f, 0.f};
    acc = __builtin_amdgcn_mfma_f32_16x16x32_bf16(a[0], mfp[(jb * 4 + 0) * 64 + lane], acc, 0, 0, 0);
    acc = __builtin_amdgcn_mfma_f32_16x16x32_bf16(a[1], mfp[(jb * 4 + 1) * 64 + lane], acc, 0, 0, 0);
    acc = __builtin_amdgcn_mfma_f32_16x16x32_bf16(a[2], mfp[(jb * 4 + 2) * 64 + lane], acc, 0, 0, 0);
    acc = __builtin_amdgcn_mfma_f32_16x16x32_bf16(a[3], mfp[(jb * 4 + 3) * 64 + lane], acc, 0, 0, 0);
    int col = (jb & 3) * 16 + m;
    if (jb < 4) {
#pragma unroll
      for (int r = 0; r < 4; ++r)
        lp[(g * 4 + r) * 72 + col] = (unsigned short)bfr(acc[r]);
      if (writePRA) {
#pragma unroll
        for (int r = 0; r < 4; ++r)
          PRA[(size_t)(tile * 16 + g * 4 + r) * 64 + col] = acc[r];
      }
    } else {
#pragma unroll
      for (int r = 0; r < 4; ++r)
        PRU[(size_t)(tile * 16 + g * 4 + r) * 64 + col] = acc[r];
    }
  }
  __syncthreads();

  int m2 = lane >> 2, lo = lane & 3;
  uint4 w0 = *(const uint4*)&ldsP[wib][m2 * 72 + lo * 8];        // cols [lo*8, +8)
  uint4 w1 = *(const uint4*)&ldsP[wib][m2 * 72 + 32 + lo * 8];   // cols [32+lo*8, +8)
  uint4* __restrict__ pp = &PRAh[(size_t)(tile * 16 + m2) * 8];
  pp[lo] = w0;       // bytes [0,64) contiguous across the 4-lane group
  pp[4 + lo] = w1;   // bytes [64,128)
}

// ---------------------------------------------------------------------------
// Counting sort: hist -> 3-phase scan
// ---------------------------------------------------------------------------
__global__ __launch_bounds__(256) void k_hist(const int* __restrict__ idx,
                                              int* __restrict__ hist) {
  int e = blockIdx.x * 256 + threadIdx.x;
  if (e < NE) atomicAdd(&hist[idx[NE + e]], 1);
}

__global__ __launch_bounds__(1024) void k_scanA(const int* __restrict__ hist,
                                                int* __restrict__ strt,
                                                int* __restrict__ bsum) {
  __shared__ int lds[1024];
  int t = threadIdx.x;
  int i = blockIdx.x * 1024 + t;
  int v = (i < NN) ? hist[i] : 0;
  lds[t] = v;
  __syncthreads();
  for (int off = 1; off < 1024; off <<= 1) {
    int u = (t >= off) ? lds[t - off] : 0;
    __syncthreads();
    lds[t] += u;
    __syncthreads();
  }
  if (i < NN) strt[i] = lds[t] - v;
  if (t == 1023) bsum[blockIdx.x] = lds[1023];
}

__global__ __launch_bounds__(128) void k_scanB(const int* __restrict__ bsum,
                                               int* __restrict__ boff,
                                               int* __restrict__ strt,
                                               int nblocks) {
  __shared__ int lds[128];
  int t = threadIdx.x;
  int v = (t < nblocks) ? bsum[t] : 0;
  lds[t] = v;
  __syncthreads();
  for (int off = 1; off < 128; off <<= 1) {
    int u = (t >= off) ? lds[t - off] : 0;
    __syncthreads();
    lds[t] += u;
    __syncthreads();
  }
  if (t < nblocks) boff[t] = lds[t] - v;
  if (t == 127) strt[NN] = lds[127];
}

__global__ __launch_bounds__(1024) void k_scanC(int* __restrict__ strt,
                                                const int* __restrict__ boff) {
  int i = blockIdx.x * 1024 + threadIdx.x;
  if (i < NN) strt[i] += boff[blockIdx.x];
}

// ---------------------------------------------------------------------------
// k_msgh: wave per 16-edge tile. PRAh prefetch at entry. MFMA q=ef@B + bias
// -> LDS transpose -> add PRAh, relu -> TWO fully-contiguous 64B store
// instructions per edge row (qp[lo], qp[4+lo]).
// ---------------------------------------------------------------------------
__global__ __launch_bounds__(256) void k_msgh(
    const int* __restrict__ idx, const int* __restrict__ strt,
    int* __restrict__ cursor, const float* __restrict__ ef,
    const uint4* __restrict__ Bfrag, const float* __restrict__ c,
    const uint4* __restrict__ PRAh, unsigned short* __restrict__ hS) {
  __shared__ unsigned short ldsQ[4][16 * 72];
  __shared__ int slotA[4][16];
  int wib = threadIdx.x >> 6;
  int lane = threadIdx.x & 63;
  int m = lane & 15, g = lane >> 4;
  int tile = blockIdx.x * 4 + wib;

  // early: PRAh loads for this lane's phase-6 quarters (contiguous mapping)
  int m2 = lane >> 2, lo = lane & 3;
  int src6 = idx[tile * 16 + m2];
  uint4 p0 = PRAh[(size_t)src6 * 8 + lo];       // cols [lo*8, +8)
  uint4 p1 = PRAh[(size_t)src6 * 8 + 4 + lo];   // cols [32+lo*8, +8)

  if (lane < 16) {
    int e = tile * 16 + m;
    int dst = idx[NE + e];
    int pos = atomicAdd(&cursor[dst], 1);
    slotA[wib][m] = strt[dst] + pos;
  }

  const float* __restrict__ rp = &ef[(size_t)(tile * 16 + m) * 32 + g * 8];
  float4 f0 = *(const float4*)rp;
  float4 f1 = *(const float4*)(rp + 4);
  bf16x8 a;
  a[0] = (short)bfr(f0.x); a[1] = (short)bfr(f0.y);
  a[2] = (short)bfr(f0.z); a[3] = (short)bfr(f0.w);
  a[4] = (short)bfr(f1.x); a[5] = (short)bfr(f1.y);
  a[6] = (short)bfr(f1.z); a[7] = (short)bfr(f1.w);

  const bf16x8* __restrict__ bfp = (const bf16x8*)Bfrag;
  bf16x8 b0 = bfp[0 * 64 + lane];
  bf16x8 b1 = bfp[1 * 64 + lane];
  bf16x8 b2 = bfp[2 * 64 + lane];
  bf16x8 b3 = bfp[3 * 64 + lane];
  float cl0 = c[0 * 16 + m], cl1 = c[1 * 16 + m];
  float cl2 = c[2 * 16 + m], cl3 = c[3 * 16 + m];

  f32x4 z = {0.f, 0.f, 0.f, 0.f};
  f32x4 q0 = __builtin_amdgcn_mfma_f32_16x16x32_bf16(a, b0, z, 0, 0, 0);
  f32x4 q1 = __builtin_amdgcn_mfma_f32_16x16x32_bf16(a, b1, z, 0, 0, 0);
  f32x4 q2 = __builtin_amdgcn_mfma_f32_16x16x32_bf16(a, b2, z, 0, 0, 0);
  f32x4 q3 = __builtin_amdgcn_mfma_f32_16x16x32_bf16(a, b3, z, 0, 0, 0);

  unsigned short* __restrict__ lq = &ldsQ[wib][0];
#pragma unroll
  for (int r = 0; r < 4; ++r) {
    int mp = g * 4 + r;
    lq[mp * 72 + 0 * 16 + m] = (unsigned short)bfr(q0[r] + cl0);
    lq[mp * 72 + 1 * 16 + m] = (unsigned short)bfr(q1[r] + cl1);
    lq[mp * 72 + 2 * 16 + m] = (unsigned short)bfr(q2[r] + cl2);
    lq[mp * 72 + 3 * 16 + m] = (unsigned short)bfr(q3[r] + cl3);
  }
  __syncthreads();

  uint4 w0 = *(const uint4*)&ldsQ[wib][m2 * 72 + lo * 8];
  uint4 w1 = *(const uint4*)&ldsQ[wib][m2 * 72 + 32 + lo * 8];
  int slot = slotA[wib][m2];
  uint4 h0 = addrelu4(w0, p0);
  uint4 h1 = addrelu4(w1, p1);
  uint4* __restrict__ qp = (uint4*)(hS + (size_t)slot * 64);
  qp[lo] = h0;       // bytes [0,64) of the row, contiguous per instruction
  qp[4 + lo] = h1;   // bytes [64,128)
}

// ---------------------------------------------------------------------------
// k_sum: streaming segment-sum; outputs bf16-packed Hb (pair-pack via shfl).
// ---------------------------------------------------------------------------
__global__ __launch_bounds__(256) void k_sum(
    const unsigned short* __restrict__ hS, const int* __restrict__ strt,
    unsigned* __restrict__ Hb) {
  int wib = threadIdx.x >> 6;
  int lane = threadIdx.x & 63;
  int n = blockIdx.x * 4 + wib;
  if (n >= NN) return;
  int s0 = strt[n], s1 = strt[n + 1];
  float acc = 0.f;
  int s = s0;
  for (; s + 4 <= s1; s += 4) {
    unsigned short a0 = hS[(size_t)(s + 0) * 64 + lane];
    unsigned short a1 = hS[(size_t)(s + 1) * 64 + lane];
    unsigned short a2 = hS[(size_t)(s + 2) * 64 + lane];
    unsigned short a3 = hS[(size_t)(s + 3) * 64 + lane];
    acc += (bf2f(a0) + bf2f(a1)) + (bf2f(a2) + bf2f(a3));
  }
  for (; s < s1; ++s) acc += bf2f(hS[(size_t)s * 64 + lane]);
  float other = __shfl_xor(acc, 1);
  if ((lane & 1) == 0)
    Hb[(size_t)n * 32 + (lane >> 1)] = bfr(acc) | (bfr(other) << 16);
}

// ---------------------------------------------------------------------------
// k_update5: MFMA update MLP; H read directly as bf16 frags from Hb.
// ---------------------------------------------------------------------------
__global__ __launch_bounds__(256) void k_update5(
    const unsigned* __restrict__ Hb, const int* __restrict__ strt,
    const float* __restrict__ PRU,
    const uint4* __restrict__ W2Uf, const float* __restrict__ d2,
    const float* __restrict__ bu1,
    const uint4* __restrict__ wu2f, const float* __restrict__ bu2,
    float* __restrict__ out) {
  __shared__ unsigned short ldsH[4][16 * 72];
  int wib = threadIdx.x >> 6;
  int lane = threadIdx.x & 63;
  int tile = blockIdx.x * 4 + wib;
  if (tile >= NN / 16) return;
  int m = lane & 15, g = lane >> 4;
  int node = tile * 16 + m;

  bf16x8 ah[2];
  ah[0] = *(const bf16x8*)&Hb[(size_t)node * 32 + 0 * 16 + g * 4];
  ah[1] = *(const bf16x8*)&Hb[(size_t)node * 32 + 1 * 16 + g * 4];

  float deg[4];
#pragma unroll
  for (int r = 0; r < 4; ++r) {
    int row = tile * 16 + g * 4 + r;
    deg[r] = (float)(strt[row + 1] - strt[row]);
  }

  const bf16x8* __restrict__ w2p = (const bf16x8*)W2Uf;
  const bf16x8* __restrict__ wup = (const bf16x8*)wu2f;
  unsigned short* __restrict__ lh = &ldsH[wib][0];

#pragma unroll
  for (int jb = 0; jb < 4; ++jb) {
    f32x4 acc = {0.f, 0.f, 0.f, 0.f};
    acc = __builtin_amdgcn_mfma_f32_16x16x32_bf16(ah[0], w2p[(jb * 2 + 0) * 64 + lane], acc, 0, 0, 0);
    acc = __builtin_amdgcn_mfma_f32_16x16x32_bf16(ah[1], w2p[(jb * 2 + 1) * 64 + lane], acc, 0, 0, 0);
    int col = jb * 16 + m;
    float dc = d2[col], bc = bu1[col];
#pragma unroll
    for (int r = 0; r < 4; ++r) {
      int row = tile * 16 + g * 4 + r;
      float pre = acc[r] + PRU[(size_t)row * 64 + col] + deg[r] * dc + bc;
      lh[(g * 4 + r) * 72 + col] = (unsigned short)bfr(fmaxf(pre, 0.f));
    }
  }
  __syncthreads();

  bf16x8 a2[2];
  a2[0] = *(const bf16x8*)&lh[m * 72 + 0 * 32 + g * 8];
  a2[1] = *(const bf16x8*)&lh[m * 72 + 1 * 32 + g * 8];
#pragma unroll
  for (int jb = 0; jb < 4; ++jb) {
    f32x4 acc = {0.f, 0.f, 0.f, 0.f};
    acc = __builtin_amdgcn_mfma_f32_16x16x32_bf16(a2[0], wup[(jb * 2 + 0) * 64 + lane], acc, 0, 0, 0);
    acc = __builtin_amdgcn_mfma_f32_16x16x32_bf16(a2[1], wup[(jb * 2 + 1) * 64 + lane], acc, 0, 0, 0);
    int col = jb * 16 + m;
    float bc = bu2[col];
#pragma unroll
    for (int r = 0; r < 4; ++r) {
      int row = tile * 16 + g * 4 + r;
      out[(size_t)row * 64 + col] = acc[r] + bc;
    }
  }
}

// ---------------------------------------------------------------------------
// Fallback (ws too small): round-1 atomic scatter path
// ---------------------------------------------------------------------------
__global__ __launch_bounds__(256) void k_edge_at(
    const int* __restrict__ idx, const float* __restrict__ ef,
    const float* __restrict__ B, const float* __restrict__ c,
    const float* __restrict__ wm2, const float* __restrict__ bm2,
    const float* __restrict__ PRA, float* __restrict__ agg) {
  int e = blockIdx.x * 256 + threadIdx.x;
  if (e >= NE) return;
  int src = idx[e];
  int dst = idx[NE + e];
  float efr[32];
#pragma unroll
  for (int k = 0; k < 32; k += 4)
    *(float4*)&efr[k] = *(const float4*)&ef[(size_t)e * 32 + k];
  float m[64];
#pragma unroll
  for (int o = 0; o < 64; ++o) m[o] = bm2[o];
  const float* __restrict__ prs = &PRA[(size_t)src * 64];
#pragma unroll 1
  for (int jc = 0; jc < 64; jc += 16) {
    float q[16];
#pragma unroll
    for (int jj = 0; jj < 16; ++jj) q[jj] = c[jc + jj];
#pragma unroll
    for (int k = 0; k < 32; ++k) {
      float ev = efr[k];
#pragma unroll
      for (int jj = 0; jj < 16; ++jj) q[jj] += ev * B[k * 64 + jc + jj];
    }
#pragma unroll
    for (int jj = 0; jj < 16; ++jj) {
      float h = fmaxf(prs[jc + jj] + q[jj], 0.f);
#pragma unroll
      for (int o = 0; o < 64; ++o) m[o] += h * wm2[(jc + jj) * 64 + o];
    }
  }
  float* __restrict__ ap = &agg[(size_t)dst * 64];
#pragma unroll
  for (int o = 0; o < 64; ++o) atomicAdd(&ap[o], m[o]);
}

__global__ __launch_bounds__(256) void k_update_at(
    const float* __restrict__ agg, const float* __restrict__ PRU,
    const float* __restrict__ wu1, const float* __restrict__ bu1,
    const float* __restrict__ wu2, const float* __restrict__ bu2,
    float* __restrict__ out) {
  int n = blockIdx.x * 256 + threadIdx.x;
  if (n >= NN) return;
  float ar[64];
#pragma unroll
  for (int k = 0; k < 64; k += 4)
    *(float4*)&ar[k] = *(const float4*)&agg[(size_t)n * 64 + k];
  float acc[64];
#pragma unroll
  for (int o = 0; o < 64; ++o) acc[o] = bu2[o];
  const float* __restrict__ prs = &PRU[(size_t)n * 64];
#pragma unroll 1
  for (int jc = 0; jc < 64; jc += 16) {
    float q[16];
#pragma unroll
    for (int jj = 0; jj < 16; ++jj) q[jj] = bu1[jc + jj];
#pragma unroll
    for (int k = 0; k < 64; ++k) {
      float av = ar[k];
#pragma unroll
      for (int jj = 0; jj < 16; ++jj) q[jj] += av * wu1[(128 + k) * 64 + jc + jj];
    }
#pragma unroll
    for (int jj = 0; jj < 16; ++jj) {
      float h = fmaxf(prs[jc + jj] + q[jj], 0.f);
#pragma unroll
      for (int o = 0; o < 64; ++o) acc[o] += h * wu2[(jc + jj) * 64 + o];
    }
  }
#pragma unroll
  for (int o = 0; o < 64; o += 4)
    *(float4*)&out[(size_t)n * 64 + o] = make_float4(acc[o], acc[o + 1], acc[o + 2], acc[o + 3]);
}

extern "C" void kernel_launch(void* const* d_in, const int* in_sizes, int n_in,
                              void* d_out, int out_size, void* d_ws, size_t ws_size,
                              hipStream_t stream) {
  const float* nf  = (const float*)d_in[0];
  const int*   idx = (const int*)d_in[1];
  const float* ef  = (const float*)d_in[2];
  const float* wn  = (const float*)d_in[3];
  const float* bn  = (const float*)d_in[4];
  const float* we  = (const float*)d_in[5];
  const float* be  = (const float*)d_in[6];
  const float* wm1 = (const float*)d_in[7];
  const float* bm1 = (const float*)d_in[8];
  const float* wm2 = (const float*)d_in[9];
  const float* bm2 = (const float*)d_in[10];
  const float* wu1 = (const float*)d_in[11];
  const float* bu1 = (const float*)d_in[12];
  const float* wu2 = (const float*)d_in[13];
  const float* bu2 = (const float*)d_in[14];
  float* out = (float*)d_out;

  float* ws   = (float*)d_ws;
  float* M    = ws + OFF_M;
  float* B    = ws + OFF_B;
  float* c    = ws + OFF_C;
  float* W2U  = ws + OFF_W2U;
  float* d2   = ws + OFF_D2;
  uint4* Bfrg = (uint4*)(ws + OFF_BFRG);
  uint4* Mfrg = (uint4*)(ws + OFF_MFRG);
  uint4* W2Uf = (uint4*)(ws + OFF_W2UF);
  uint4* wu2f = (uint4*)(ws + OFF_WU2F);
  int*   bsum = (int*)(ws + OFF_BSUM);
  int*   boff = (int*)(ws + OFF_BOFF);
  float* PRA  = ws + OFF_PRA;
  uint4* PRAh = (uint4*)(ws + OFF_PRAH);
  float* PRU  = ws + OFF_PRU;
  float* H    = ws + OFF_H;
  unsigned* Hb = (unsigned*)(ws + OFF_H);
  int*   hist = (int*)(ws + OFF_HIST);
  int*   cur  = (int*)(ws + OFF_CUR);
  int*   strt = (int*)(ws + OFF_STRT);
  unsigned short* hS = (unsigned short*)(ws + OFF_HS);

  const int SCAN_BLOCKS = (NN + 1023) / 1024;  // 98
  const int FOLD_THREADS = 16384 + 2048 + 64 + 4096 + 64 + 256 + 2048 + 512 + 512;
  const int NTILE = NN / 16;  // 6250

  int fast = (ws_size >= (size_t)WS_UNITS * 4);

  k_fold<<<(FOLD_THREADS + 255) / 256, 256, 0, stream>>>(
      wn, bn, we, be, wm1, bm1, wm2, bm2, wu1, wu2,
      M, B, c, W2U, d2, Bfrg, Mfrg, W2Uf, wu2f);
  k_node2<<<(NTILE + 3) / 4, 256, 0, stream>>>(nf, Mfrg, PRA, PRAh, PRU,
                                               fast ? 0 : 1);

  if (fast) {
    hipMemsetAsync(hist, 0, (size_t)2 * NN * sizeof(int), stream);
    k_hist<<<(NE + 255) / 256, 256, 0, stream>>>(idx, hist);
    k_scanA<<<SCAN_BLOCKS, 1024, 0, stream>>>(hist, strt, bsum);
    k_scanB<<<1, 128, 0, stream>>>(bsum, boff, strt, SCAN_BLOCKS);
    k_scanC<<<SCAN_BLOCKS, 1024, 0, stream>>>(strt, boff);
    k_msgh<<<NE / 16 / 4, 256, 0, stream>>>(idx, strt, cur, ef, Bfrg, c,
                                            PRAh, hS);
    k_sum<<<(NN + 3) / 4, 256, 0, stream>>>(hS, strt, Hb);
    k_update5<<<(NTILE + 3) / 4, 256, 0, stream>>>(
        Hb, strt, PRU, W2Uf, d2, bu1, wu2f, bu2, out);
  } else {
    hipMemsetAsync(H, 0, (size_t)NN * 64 * sizeof(float), stream);
    k_edge_at<<<(NE + 255) / 256, 256, 0, stream>>>(idx, ef, B, c, wm2, bm2, PRA, H);
    k_update_at<<<(NN + 255) / 256, 256, 0, stream>>>(
        H, PRU, wu1, bu1, wu2, bu2, out);
  }
}

// Round 19
// 340.486 us; speedup vs baseline: 1.9277x; 1.0582x over previous
//
#include <hip/hip_runtime.h>

#define NN 100000
#define NE 1600000

typedef __attribute__((ext_vector_type(8))) short bf16x8;
typedef __attribute__((ext_vector_type(4))) float f32x4;

// ---------------------------------------------------------------------------
// Workspace layout in 4-byte units (~302 MB; round-5 tier-1 proved >=540 MB)
// ---------------------------------------------------------------------------
#define OFF_M    0                         // 128*128 folded (fallback)
#define OFF_B    (OFF_M + 16384)           // 32*64 (fallback)
#define OFF_C    (OFF_B + 2048)            // 64
#define OFF_W2U  (OFF_C + 64)              // 64*64 f32 (fallback)
#define OFF_D2   (OFF_W2U + 4096)          // 64
#define OFF_BFRG (OFF_D2 + 64)             // 4*64 uint4
#define OFF_MFRG (OFF_BFRG + 1024)         // 32*64 uint4
#define OFF_W2UF (OFF_MFRG + 8192)         // 8*64 uint4
#define OFF_WU2F (OFF_W2UF + 2048)         // 8*64 uint4
#define OFF_BSUM (OFF_WU2F + 2048)         // 128
#define OFF_BOFF (OFF_BSUM + 128)          // 128
#define OFF_PRA  (OFF_BOFF + 128)          // NN*64 f32 (fallback only)
#define OFF_PRAH (OFF_PRA + NN * 64)       // NN*32: PRA bf16
#define OFF_PRU  (OFF_PRAH + NN * 32)      // NN*64
#define OFF_H    (OFF_PRU + NN * 64)       // NN*64 (fallback agg); fast: Hb NN*32
#define OFF_HIST (OFF_H + NN * 64)         // NN
#define OFF_STRT (OFF_HIST + NN)           // NN+1 (+pad)
#define OFF_POS  (OFF_STRT + NN + 4)       // NE: rank of edge within dst segment
#define OFF_HS   (OFF_POS + NE)            // NE*32 dwords (bf16 rows)
#define WS_UNITS (OFF_HS + NE * 32)

__device__ __forceinline__ unsigned bfr(float x) {
  unsigned u = __float_as_uint(x);
  return (u + 0x7fffu + ((u >> 16) & 1u)) >> 16;
}
__device__ __forceinline__ float bf2f(unsigned short h) {
  return __uint_as_float(((unsigned)h) << 16);
}
__device__ __forceinline__ unsigned addrelu1(unsigned qa, unsigned pb) {
  float lo = __uint_as_float((qa & 0xffffu) << 16) +
             __uint_as_float((pb & 0xffffu) << 16);
  float hi = __uint_as_float(qa & 0xffff0000u) +
             __uint_as_float(pb & 0xffff0000u);
  lo = fmaxf(lo, 0.f);
  hi = fmaxf(hi, 0.f);
  return bfr(lo) | (bfr(hi) << 16);
}
__device__ __forceinline__ uint4 addrelu4(uint4 q, uint4 p) {
  return make_uint4(addrelu1(q.x, p.x), addrelu1(q.y, p.y),
                    addrelu1(q.z, p.z), addrelu1(q.w, p.w));
}

// ---------------------------------------------------------------------------
// Weight folding + bf16 fragment packs (unchanged)
// ---------------------------------------------------------------------------
__global__ __launch_bounds__(256) void k_fold(
    const float* __restrict__ wn, const float* __restrict__ bn,
    const float* __restrict__ we, const float* __restrict__ be,
    const float* __restrict__ wm1, const float* __restrict__ bm1,
    const float* __restrict__ wm2, const float* __restrict__ bm2,
    const float* __restrict__ wu1, const float* __restrict__ wu2,
    float* __restrict__ M, float* __restrict__ B, float* __restrict__ c,
    float* __restrict__ W2U, float* __restrict__ d2,
    uint4* __restrict__ Bfrag, uint4* __restrict__ Mfrag,
    uint4* __restrict__ W2Uf, uint4* __restrict__ wu2f) {
  int t = blockIdx.x * 256 + threadIdx.x;
  if (t < 16384) {
    int k = t >> 7, j = t & 127;
    float acc;
    if (j < 64) {
      acc = 0.f;
      for (int h = 0; h < 64; ++h) acc += wn[k * 64 + h] * wm1[h * 64 + j];
    } else {
      acc = wu1[k * 64 + (j - 64)];
    }
    M[t] = acc;
  } else if (t < 16384 + 2048) {
    int u = t - 16384;
    int k = u >> 6, j = u & 63;
    float acc = 0.f;
    for (int h = 0; h < 64; ++h) acc += we[k * 64 + h] * wm1[(64 + h) * 64 + j];
    B[u] = acc;
  } else if (t < 16384 + 2048 + 64) {
    int j = t - (16384 + 2048);
    float acc = bm1[j];
    for (int h = 0; h < 64; ++h)
      acc += bn[h] * wm1[h * 64 + j] + be[h] * wm1[(64 + h) * 64 + j];
    c[j] = acc;
  } else if (t < 16384 + 2048 + 64 + 4096) {
    int u = t - (16384 + 2048 + 64);
    int k = u >> 6, j = u & 63;
    float acc = 0.f;
    for (int h = 0; h < 64; ++h) acc += wm2[k * 64 + h] * wu1[(128 + h) * 64 + j];
    W2U[u] = acc;
  } else if (t < 16384 + 2048 + 64 + 4096 + 64) {
    int j = t - (16384 + 2048 + 64 + 4096);
    float acc = 0.f;
    for (int h = 0; h < 64; ++h) acc += bm2[h] * wu1[(128 + h) * 64 + j];
    d2[j] = acc;
  } else if (t < 16384 + 2048 + 64 + 4096 + 64 + 256) {
    int u = t - (16384 + 2048 + 64 + 4096 + 64);
    int jb = u >> 6, l = u & 63;
    int g = l >> 4, n = l & 15;
    unsigned s[8];
#pragma unroll
    for (int i = 0; i < 8; ++i) {
      int k = g * 8 + i;
      int j = jb * 16 + n;
      float acc = 0.f;
      for (int h = 0; h < 64; ++h)
        acc += we[k * 64 + h] * wm1[(64 + h) * 64 + j];
      s[i] = bfr(acc);
    }
    Bfrag[jb * 64 + l] = make_uint4(s[0] | (s[1] << 16), s[2] | (s[3] << 16),
                                    s[4] | (s[5] << 16), s[6] | (s[7] << 16));
  } else if (t < 16384 + 2048 + 64 + 4096 + 64 + 256 + 2048) {
    int u = t - (16384 + 2048 + 64 + 4096 + 64 + 256);
    int jb = u >> 8, kb = (u >> 6) & 3, l = u & 63;
    int g = l >> 4, n = l & 15;
    int j = jb * 16 + n;
    unsigned s[8];
#pragma unroll
    for (int i = 0; i < 8; ++i) {
      int k = kb * 32 + g * 8 + i;
      float acc;
      if (j < 64) {
        acc = 0.f;
        for (int h = 0; h < 64; ++h) acc += wn[k * 64 + h] * wm1[h * 64 + j];
      } else {
        acc = wu1[k * 64 + (j - 64)];
      }
      s[i] = bfr(acc);
    }
    Mfrag[(jb * 4 + kb) * 64 + l] =
        make_uint4(s[0] | (s[1] << 16), s[2] | (s[3] << 16),
                   s[4] | (s[5] << 16), s[6] | (s[7] << 16));
  } else if (t < 16384 + 2048 + 64 + 4096 + 64 + 256 + 2048 + 512) {
    int u = t - (16384 + 2048 + 64 + 4096 + 64 + 256 + 2048);
    int jk = u >> 6, l = u & 63;
    int jb = jk >> 1, kb = jk & 1;
    int g = l >> 4, n = l & 15;
    int j = jb * 16 + n;
    unsigned s[8];
#pragma unroll
    for (int i = 0; i < 8; ++i) {
      int k = kb * 32 + g * 8 + i;
      float acc = 0.f;
      for (int h = 0; h < 64; ++h)
        acc += wm2[k * 64 + h] * wu1[(128 + h) * 64 + j];
      s[i] = bfr(acc);
    }
    W2Uf[jk * 64 + l] = make_uint4(s[0] | (s[1] << 16), s[2] | (s[3] << 16),
                                   s[4] | (s[5] << 16), s[6] | (s[7] << 16));
  } else if (t < 16384 + 2048 + 64 + 4096 + 64 + 256 + 2048 + 512 + 512) {
    int u = t - (16384 + 2048 + 64 + 4096 + 64 + 256 + 2048 + 512);
    int jk = u >> 6, l = u & 63;
    int jb = jk >> 1, kb = jk & 1;
    int g = l >> 4, n = l & 15;
    unsigned s[8];
#pragma unroll
    for (int i = 0; i < 8; ++i)
      s[i] = bfr(wu2[(size_t)(kb * 32 + g * 8 + i) * 64 + jb * 16 + n]);
    wu2f[jk * 64 + l] = make_uint4(s[0] | (s[1] << 16), s[2] | (s[3] << 16),
                                   s[4] | (s[5] << 16), s[6] | (s[7] << 16));
  }
}

// ---------------------------------------------------------------------------
// k_node2: MFMA node precompute -> PRAh (bf16 transposed burst) + PRU f32.
// ---------------------------------------------------------------------------
__global__ __launch_bounds__(256) void k_node2(
    const float* __restrict__ nf, const uint4* __restrict__ Mfrag,
    float* __restrict__ PRA, uint4* __restrict__ PRAh,
    float* __restrict__ PRU, int writePRA) {
  __shared__ unsigned short ldsP[4][16 * 72];
  int wib = threadIdx.x >> 6;
  int lane = threadIdx.x & 63;
  int tile = blockIdx.x * 4 + wib;
  if (tile >= NN / 16) return;
  int m = lane & 15, g = lane >> 4;
  int node = tile * 16 + m;

  bf16x8 a[4];
#pragma unroll
  for (int kb = 0; kb < 4; ++kb) {
    const float* __restrict__ rp = &nf[(size_t)node * 128 + kb * 32 + g * 8];
    float4 f0 = *(const float4*)rp;
    float4 f1 = *(const float4*)(rp + 4);
    bf16x8 v;
    v[0] = (short)bfr(f0.x); v[1] = (short)bfr(f0.y);
    v[2] = (short)bfr(f0.z); v[3] = (short)bfr(f0.w);
    v[4] = (short)bfr(f1.x); v[5] = (short)bfr(f1.y);
    v[6] = (short)bfr(f1.z); v[7] = (short)bfr(f1.w);
    a[kb] = v;
  }

  const bf16x8* __restrict__ mfp = (const bf16x8*)Mfrag;
  unsigned short* __restrict__ lp = &ldsP[wib][0];
#pragma unroll
  for (int jb = 0; jb < 8; ++jb) {
    f32x4 acc = {0.f, 0.f, 0.f, 0.f};
    acc = __builtin_amdgcn_mfma_f32_16x16x32_bf16(a[0], mfp[(jb * 4 + 0) * 64 + lane], acc, 0, 0, 0);
    acc = __builtin_amdgcn_mfma_f32_16x16x32_bf16(a[1], mfp[(jb * 4 + 1) * 64 + lane], acc, 0, 0, 0);
    acc = __builtin_amdgcn_mfma_f32_16x16x32_bf16(a[2], mfp[(jb * 4 + 2) * 64 + lane], acc, 0, 0, 0);
    acc = __builtin_amdgcn_mfma_f32_16x16x32_bf16(a[3], mfp[(jb * 4 + 3) * 64 + lane], acc, 0, 0, 0);
    int col = (jb & 3) * 16 + m;
    if (jb < 4) {
#pragma unroll
      for (int r = 0; r < 4; ++r)
        lp[(g * 4 + r) * 72 + col] = (unsigned short)bfr(acc[r]);
      if (writePRA) {
#pragma unroll
        for (int r = 0; r < 4; ++r)
          PRA[(size_t)(tile * 16 + g * 4 + r) * 64 + col] = acc[r];
      }
    } else {
#pragma unroll
      for (int r = 0; r < 4; ++r)
        PRU[(size_t)(tile * 16 + g * 4 + r) * 64 + col] = acc[r];
    }
  }
  __syncthreads();

  int m2 = lane >> 2, lo = lane & 3;
  uint4 w0 = *(const uint4*)&ldsP[wib][m2 * 72 + lo * 8];
  uint4 w1 = *(const uint4*)&ldsP[wib][m2 * 72 + 32 + lo * 8];
  uint4* __restrict__ pp = &PRAh[(size_t)(tile * 16 + m2) * 8];
  pp[lo] = w0;
  pp[4 + lo] = w1;
}

// ---------------------------------------------------------------------------
// Counting sort. k_hist's atomicAdd return value IS the within-segment rank:
// persist it to posOf so the message kernel needs no atomics at all.
// ---------------------------------------------------------------------------
__global__ __launch_bounds__(256) void k_hist(const int* __restrict__ idx,
                                              int* __restrict__ hist,
                                              int* __restrict__ posOf) {
  int e = blockIdx.x * 256 + threadIdx.x;
  if (e < NE) posOf[e] = atomicAdd(&hist[idx[NE + e]], 1);
}

__global__ __launch_bounds__(1024) void k_scanA(const int* __restrict__ hist,
                                                int* __restrict__ strt,
                                                int* __restrict__ bsum) {
  __shared__ int lds[1024];
  int t = threadIdx.x;
  int i = blockIdx.x * 1024 + t;
  int v = (i < NN) ? hist[i] : 0;
  lds[t] = v;
  __syncthreads();
  for (int off = 1; off < 1024; off <<= 1) {
    int u = (t >= off) ? lds[t - off] : 0;
    __syncthreads();
    lds[t] += u;
    __syncthreads();
  }
  if (i < NN) strt[i] = lds[t] - v;
  if (t == 1023) bsum[blockIdx.x] = lds[1023];
}

__global__ __launch_bounds__(128) void k_scanB(const int* __restrict__ bsum,
                                               int* __restrict__ boff,
                                               int* __restrict__ strt,
                                               int nblocks) {
  __shared__ int lds[128];
  int t = threadIdx.x;
  int v = (t < nblocks) ? bsum[t] : 0;
  lds[t] = v;
  __syncthreads();
  for (int off = 1; off < 128; off <<= 1) {
    int u = (t >= off) ? lds[t - off] : 0;
    __syncthreads();
    lds[t] += u;
    __syncthreads();
  }
  if (t < nblocks) boff[t] = lds[t] - v;
  if (t == 127) strt[NN] = lds[127];
}

__global__ __launch_bounds__(1024) void k_scanC(int* __restrict__ strt,
                                                const int* __restrict__ boff) {
  int i = blockIdx.x * 1024 + threadIdx.x;
  if (i < NN) strt[i] += boff[blockIdx.x];
}

// ---------------------------------------------------------------------------
// k_msgh: wave per 16-edge tile. ZERO atomics: slot = strt[dst] + posOf[e].
// PRAh prefetch at entry; MFMA q=ef@B + bias -> LDS transpose -> add PRAh,
// relu -> two contiguous 64B stores per edge row.
// ---------------------------------------------------------------------------
__global__ __launch_bounds__(256) void k_msgh(
    const int* __restrict__ idx, const int* __restrict__ strt,
    const int* __restrict__ posOf, const float* __restrict__ ef,
    const uint4* __restrict__ Bfrag, const float* __restrict__ c,
    const uint4* __restrict__ PRAh, unsigned short* __restrict__ hS) {
  __shared__ unsigned short ldsQ[4][16 * 72];
  int wib = threadIdx.x >> 6;
  int lane = threadIdx.x & 63;
  int m = lane & 15, g = lane >> 4;
  int tile = blockIdx.x * 4 + wib;

  // early: per-group edge (m2) metadata + PRAh loads — all plain loads
  int m2 = lane >> 2, lo = lane & 3;
  int e6 = tile * 16 + m2;
  int src6 = idx[e6];
  int dst6 = idx[NE + e6];
  int pos6 = posOf[e6];
  uint4 p0 = PRAh[(size_t)src6 * 8 + lo];
  uint4 p1 = PRAh[(size_t)src6 * 8 + 4 + lo];
  int slot = strt[dst6] + pos6;

  const float* __restrict__ rp = &ef[(size_t)(tile * 16 + m) * 32 + g * 8];
  float4 f0 = *(const float4*)rp;
  float4 f1 = *(const float4*)(rp + 4);
  bf16x8 a;
  a[0] = (short)bfr(f0.x); a[1] = (short)bfr(f0.y);
  a[2] = (short)bfr(f0.z); a[3] = (short)bfr(f0.w);
  a[4] = (short)bfr(f1.x); a[5] = (short)bfr(f1.y);
  a[6] = (short)bfr(f1.z); a[7] = (short)bfr(f1.w);

  const bf16x8* __restrict__ bfp = (const bf16x8*)Bfrag;
  bf16x8 b0 = bfp[0 * 64 + lane];
  bf16x8 b1 = bfp[1 * 64 + lane];
  bf16x8 b2 = bfp[2 * 64 + lane];
  bf16x8 b3 = bfp[3 * 64 + lane];
  float cl0 = c[0 * 16 + m], cl1 = c[1 * 16 + m];
  float cl2 = c[2 * 16 + m], cl3 = c[3 * 16 + m];

  f32x4 z = {0.f, 0.f, 0.f, 0.f};
  f32x4 q0 = __builtin_amdgcn_mfma_f32_16x16x32_bf16(a, b0, z, 0, 0, 0);
  f32x4 q1 = __builtin_amdgcn_mfma_f32_16x16x32_bf16(a, b1, z, 0, 0, 0);
  f32x4 q2 = __builtin_amdgcn_mfma_f32_16x16x32_bf16(a, b2, z, 0, 0, 0);
  f32x4 q3 = __builtin_amdgcn_mfma_f32_16x16x32_bf16(a, b3, z, 0, 0, 0);

  unsigned short* __restrict__ lq = &ldsQ[wib][0];
#pragma unroll
  for (int r = 0; r < 4; ++r) {
    int mp = g * 4 + r;
    lq[mp * 72 + 0 * 16 + m] = (unsigned short)bfr(q0[r] + cl0);
    lq[mp * 72 + 1 * 16 + m] = (unsigned short)bfr(q1[r] + cl1);
    lq[mp * 72 + 2 * 16 + m] = (unsigned short)bfr(q2[r] + cl2);
    lq[mp * 72 + 3 * 16 + m] = (unsigned short)bfr(q3[r] + cl3);
  }
  __syncthreads();

  uint4 w0 = *(const uint4*)&ldsQ[wib][m2 * 72 + lo * 8];
  uint4 w1 = *(const uint4*)&ldsQ[wib][m2 * 72 + 32 + lo * 8];
  uint4 h0 = addrelu4(w0, p0);
  uint4 h1 = addrelu4(w1, p1);
  uint4* __restrict__ qp = (uint4*)(hS + (size_t)slot * 64);
  qp[lo] = h0;
  qp[4 + lo] = h1;
}

// ---------------------------------------------------------------------------
// k_sum: streaming segment-sum; outputs bf16-packed Hb.
// ---------------------------------------------------------------------------
__global__ __launch_bounds__(256) void k_sum(
    const unsigned short* __restrict__ hS, const int* __restrict__ strt,
    unsigned* __restrict__ Hb) {
  int wib = threadIdx.x >> 6;
  int lane = threadIdx.x & 63;
  int n = blockIdx.x * 4 + wib;
  if (n >= NN) return;
  int s0 = strt[n], s1 = strt[n + 1];
  float acc = 0.f;
  int s = s0;
  for (; s + 4 <= s1; s += 4) {
    unsigned short a0 = hS[(size_t)(s + 0) * 64 + lane];
    unsigned short a1 = hS[(size_t)(s + 1) * 64 + lane];
    unsigned short a2 = hS[(size_t)(s + 2) * 64 + lane];
    unsigned short a3 = hS[(size_t)(s + 3) * 64 + lane];
    acc += (bf2f(a0) + bf2f(a1)) + (bf2f(a2) + bf2f(a3));
  }
  for (; s < s1; ++s) acc += bf2f(hS[(size_t)s * 64 + lane]);
  float other = __shfl_xor(acc, 1);
  if ((lane & 1) == 0)
    Hb[(size_t)n * 32 + (lane >> 1)] = bfr(acc) | (bfr(other) << 16);
}

// ---------------------------------------------------------------------------
// k_update5: MFMA update MLP; H read directly as bf16 frags from Hb.
// ---------------------------------------------------------------------------
__global__ __launch_bounds__(256) void k_update5(
    const unsigned* __restrict__ Hb, const int* __restrict__ strt,
    const float* __restrict__ PRU,
    const uint4* __restrict__ W2Uf, const float* __restrict__ d2,
    const float* __restrict__ bu1,
    const uint4* __restrict__ wu2f, const float* __restrict__ bu2,
    float* __restrict__ out) {
  __shared__ unsigned short ldsH[4][16 * 72];
  int wib = threadIdx.x >> 6;
  int lane = threadIdx.x & 63;
  int tile = blockIdx.x * 4 + wib;
  if (tile >= NN / 16) return;
  int m = lane & 15, g = lane >> 4;
  int node = tile * 16 + m;

  bf16x8 ah[2];
  ah[0] = *(const bf16x8*)&Hb[(size_t)node * 32 + 0 * 16 + g * 4];
  ah[1] = *(const bf16x8*)&Hb[(size_t)node * 32 + 1 * 16 + g * 4];

  float deg[4];
#pragma unroll
  for (int r = 0; r < 4; ++r) {
    int row = tile * 16 + g * 4 + r;
    deg[r] = (float)(strt[row + 1] - strt[row]);
  }

  const bf16x8* __restrict__ w2p = (const bf16x8*)W2Uf;
  const bf16x8* __restrict__ wup = (const bf16x8*)wu2f;
  unsigned short* __restrict__ lh = &ldsH[wib][0];

#pragma unroll
  for (int jb = 0; jb < 4; ++jb) {
    f32x4 acc = {0.f, 0.f, 0.f, 0.f};
    acc = __builtin_amdgcn_mfma_f32_16x16x32_bf16(ah[0], w2p[(jb * 2 + 0) * 64 + lane], acc, 0, 0, 0);
    acc = __builtin_amdgcn_mfma_f32_16x16x32_bf16(ah[1], w2p[(jb * 2 + 1) * 64 + lane], acc, 0, 0, 0);
    int col = jb * 16 + m;
    float dc = d2[col], bc = bu1[col];
#pragma unroll
    for (int r = 0; r < 4; ++r) {
      int row = tile * 16 + g * 4 + r;
      float pre = acc[r] + PRU[(size_t)row * 64 + col] + deg[r] * dc + bc;
      lh[(g * 4 + r) * 72 + col] = (unsigned short)bfr(fmaxf(pre, 0.f));
    }
  }
  __syncthreads();

  bf16x8 a2[2];
  a2[0] = *(const bf16x8*)&lh[m * 72 + 0 * 32 + g * 8];
  a2[1] = *(const bf16x8*)&lh[m * 72 + 1 * 32 + g * 8];
#pragma unroll
  for (int jb = 0; jb < 4; ++jb) {
    f32x4 acc = {0.f, 0.f, 0.f, 0.f};
    acc = __builtin_amdgcn_mfma_f32_16x16x32_bf16(a2[0], wup[(jb * 2 + 0) * 64 + lane], acc, 0, 0, 0);
    acc = __builtin_amdgcn_mfma_f32_16x16x32_bf16(a2[1], wup[(jb * 2 + 1) * 64 + lane], acc, 0, 0, 0);
    int col = jb * 16 + m;
    float bc = bu2[col];
#pragma unroll
    for (int r = 0; r < 4; ++r) {
      int row = tile * 16 + g * 4 + r;
      out[(size_t)row * 64 + col] = acc[r] + bc;
    }
  }
}

// ---------------------------------------------------------------------------
// Fallback (ws too small): round-1 atomic scatter path
// ---------------------------------------------------------------------------
__global__ __launch_bounds__(256) void k_edge_at(
    const int* __restrict__ idx, const float* __restrict__ ef,
    const float* __restrict__ B, const float* __restrict__ c,
    const float* __restrict__ wm2, const float* __restrict__ bm2,
    const float* __restrict__ PRA, float* __restrict__ agg) {
  int e = blockIdx.x * 256 + threadIdx.x;
  if (e >= NE) return;
  int src = idx[e];
  int dst = idx[NE + e];
  float efr[32];
#pragma unroll
  for (int k = 0; k < 32; k += 4)
    *(float4*)&efr[k] = *(const float4*)&ef[(size_t)e * 32 + k];
  float m[64];
#pragma unroll
  for (int o = 0; o < 64; ++o) m[o] = bm2[o];
  const float* __restrict__ prs = &PRA[(size_t)src * 64];
#pragma unroll 1
  for (int jc = 0; jc < 64; jc += 16) {
    float q[16];
#pragma unroll
    for (int jj = 0; jj < 16; ++jj) q[jj] = c[jc + jj];
#pragma unroll
    for (int k = 0; k < 32; ++k) {
      float ev = efr[k];
#pragma unroll
      for (int jj = 0; jj < 16; ++jj) q[jj] += ev * B[k * 64 + jc + jj];
    }
#pragma unroll
    for (int jj = 0; jj < 16; ++jj) {
      float h = fmaxf(prs[jc + jj] + q[jj], 0.f);
#pragma unroll
      for (int o = 0; o < 64; ++o) m[o] += h * wm2[(jc + jj) * 64 + o];
    }
  }
  float* __restrict__ ap = &agg[(size_t)dst * 64];
#pragma unroll
  for (int o = 0; o < 64; ++o) atomicAdd(&ap[o], m[o]);
}

__global__ __launch_bounds__(256) void k_update_at(
    const float* __restrict__ agg, const float* __restrict__ PRU,
    const float* __restrict__ wu1, const float* __restrict__ bu1,
    const float* __restrict__ wu2, const float* __restrict__ bu2,
    float* __restrict__ out) {
  int n = blockIdx.x * 256 + threadIdx.x;
  if (n >= NN) return;
  float ar[64];
#pragma unroll
  for (int k = 0; k < 64; k += 4)
    *(float4*)&ar[k] = *(const float4*)&agg[(size_t)n * 64 + k];
  float acc[64];
#pragma unroll
  for (int o = 0; o < 64; ++o) acc[o] = bu2[o];
  const float* __restrict__ prs = &PRU[(size_t)n * 64];
#pragma unroll 1
  for (int jc = 0; jc < 64; jc += 16) {
    float q[16];
#pragma unroll
    for (int jj = 0; jj < 16; ++jj) q[jj] = bu1[jc + jj];
#pragma unroll
    for (int k = 0; k < 64; ++k) {
      float av = ar[k];
#pragma unroll
      for (int jj = 0; jj < 16; ++jj) q[jj] += av * wu1[(128 + k) * 64 + jc + jj];
    }
#pragma unroll
    for (int jj = 0; jj < 16; ++jj) {
      float h = fmaxf(prs[jc + jj] + q[jj], 0.f);
#pragma unroll
      for (int o = 0; o < 64; ++o) acc[o] += h * wu2[(jc + jj) * 64 + o];
    }
  }
#pragma unroll
  for (int o = 0; o < 64; o += 4)
    *(float4*)&out[(size_t)n * 64 + o] = make_float4(acc[o], acc[o + 1], acc[o + 2], acc[o + 3]);
}

extern "C" void kernel_launch(void* const* d_in, const int* in_sizes, int n_in,
                              void* d_out, int out_size, void* d_ws, size_t ws_size,
                              hipStream_t stream) {
  const float* nf  = (const float*)d_in[0];
  const int*   idx = (const int*)d_in[1];
  const float* ef  = (const float*)d_in[2];
  const float* wn  = (const float*)d_in[3];
  const float* bn  = (const float*)d_in[4];
  const float* we  = (const float*)d_in[5];
  const float* be  = (const float*)d_in[6];
  const float* wm1 = (const float*)d_in[7];
  const float* bm1 = (const float*)d_in[8];
  const float* wm2 = (const float*)d_in[9];
  const float* bm2 = (const float*)d_in[10];
  const float* wu1 = (const float*)d_in[11];
  const float* bu1 = (const float*)d_in[12];
  const float* wu2 = (const float*)d_in[13];
  const float* bu2 = (const float*)d_in[14];
  float* out = (float*)d_out;

  float* ws   = (float*)d_ws;
  float* M    = ws + OFF_M;
  float* B    = ws + OFF_B;
  float* c    = ws + OFF_C;
  float* W2U  = ws + OFF_W2U;
  float* d2   = ws + OFF_D2;
  uint4* Bfrg = (uint4*)(ws + OFF_BFRG);
  uint4* Mfrg = (uint4*)(ws + OFF_MFRG);
  uint4* W2Uf = (uint4*)(ws + OFF_W2UF);
  uint4* wu2f = (uint4*)(ws + OFF_WU2F);
  int*   bsum = (int*)(ws + OFF_BSUM);
  int*   boff = (int*)(ws + OFF_BOFF);
  float* PRA  = ws + OFF_PRA;
  uint4* PRAh = (uint4*)(ws + OFF_PRAH);
  float* PRU  = ws + OFF_PRU;
  float* H    = ws + OFF_H;
  unsigned* Hb = (unsigned*)(ws + OFF_H);
  int*   hist = (int*)(ws + OFF_HIST);
  int*   strt = (int*)(ws + OFF_STRT);
  int*   posOf = (int*)(ws + OFF_POS);
  unsigned short* hS = (unsigned short*)(ws + OFF_HS);

  const int SCAN_BLOCKS = (NN + 1023) / 1024;  // 98
  const int FOLD_THREADS = 16384 + 2048 + 64 + 4096 + 64 + 256 + 2048 + 512 + 512;
  const int NTILE = NN / 16;  // 6250

  int fast = (ws_size >= (size_t)WS_UNITS * 4);

  k_fold<<<(FOLD_THREADS + 255) / 256, 256, 0, stream>>>(
      wn, bn, we, be, wm1, bm1, wm2, bm2, wu1, wu2,
      M, B, c, W2U, d2, Bfrg, Mfrg, W2Uf, wu2f);
  k_node2<<<(NTILE + 3) / 4, 256, 0, stream>>>(nf, Mfrg, PRA, PRAh, PRU,
                                               fast ? 0 : 1);

  if (fast) {
    hipMemsetAsync(hist, 0, (size_t)NN * sizeof(int), stream);
    k_hist<<<(NE + 255) / 256, 256, 0, stream>>>(idx, hist, posOf);
    k_scanA<<<SCAN_BLOCKS, 1024, 0, stream>>>(hist, strt, bsum);
    k_scanB<<<1, 128, 0, stream>>>(bsum, boff, strt, SCAN_BLOCKS);
    k_scanC<<<SCAN_BLOCKS, 1024, 0, stream>>>(strt, boff);
    k_msgh<<<NE / 16 / 4, 256, 0, stream>>>(idx, strt, posOf, ef, Bfrg, c,
                                            PRAh, hS);
    k_sum<<<(NN + 3) / 4, 256, 0, stream>>>(hS, strt, Hb);
    k_update5<<<(NTILE + 3) / 4, 256, 0, stream>>>(
        Hb, strt, PRU, W2Uf, d2, bu1, wu2f, bu2, out);
  } else {
    hipMemsetAsync(H, 0, (size_t)NN * 64 * sizeof(float), stream);
    k_edge_at<<<(NE + 255) / 256, 256, 0, stream>>>(idx, ef, B, c, wm2, bm2, PRA, H);
    k_update_at<<<(NN + 255) / 256, 256, 0, stream>>>(
        H, PRU, wu1, bu1, wu2, bu2, out);
  }
}